// Round 1
// baseline (367.306 us; speedup 1.0000x reference)
//
#include <hip/hip_runtime.h>
#include <math.h>

#define BB 64
#define CCH 64
#define MMH 8192
#define SLICES 8
#define KSL 1024 /* K per k1 block */
#define KCH 128  /* K per LDS chunk in k1 */
#define TMZ 128
constexpr double EPSV = 1e-5;

typedef __attribute__((ext_vector_type(8))) short bf16x8;
typedef __attribute__((ext_vector_type(8))) unsigned short u16x8;
typedef __attribute__((ext_vector_type(16))) float floatx16;

// ---------------- K1: bf16-split MFMA partial Gram + row sums ----------------
// Exact truncation split: x = t1+t2+t3 BIT-EXACT (24-bit fp32 mantissa = 3x8
// bf16 significands; bf16 exponent range == fp32 so no underflow). Cheaper than
// RNE (3 shifts + 2 masks + 2 subs vs ~18 ops) and more accurate (no 2^-25
// residual). G = 6 split products via mfma_f32_32x32x16_bf16, fp32 accum;
// dropped cross terms t2t3/t3t2/t3t3 ~ 2^-40 rel.
__global__ __launch_bounds__(256, 2) void k1_partG(const float* __restrict__ x,
                                                   float* __restrict__ Gpart,
                                                   float* __restrict__ rspart) {
  __shared__ unsigned short h1[64][KCH + 8], h2[64][KCH + 8], h3[64][KCH + 8];
  __shared__ float rred[64][4];
  const int tid = threadIdx.x;
  const int b = blockIdx.x / SLICES;
  const int s = blockIdx.x % SLICES;
  const int row = tid >> 2;
  const int seg = (tid & 3) * 32;
  const int wv = tid >> 6;
  const int lane = tid & 63;
  const int rw = wv >> 1, cw = wv & 1;
  const int mrow = 32 * rw + (lane & 31);
  const int ncol = 32 * cw + (lane & 31);
  const int koff = (lane >> 5) * 8;
  const float* xb = x + (size_t)b * CCH * MMH + (size_t)s * KSL;
  floatx16 acc = {};
  float rsum = 0.f;
  for (int c = 0; c < KSL / KCH; ++c) {
    const float* xp = xb + (size_t)row * MMH + c * KCH + seg;
    float v[32];
#pragma unroll
    for (int q = 0; q < 8; ++q) {
      float4 t = *(const float4*)(xp + 4 * q);
      v[4 * q] = t.x;
      v[4 * q + 1] = t.y;
      v[4 * q + 2] = t.z;
      v[4 * q + 3] = t.w;
    }
#pragma unroll
    for (int o = 0; o < 32; ++o) rsum += v[o];
#pragma unroll
    for (int g = 0; g < 4; ++g) {
      u16x8 a1, a2, a3;
#pragma unroll
      for (int j = 0; j < 8; ++j) {
        float f = v[8 * g + j];
        unsigned u = __float_as_uint(f);
        unsigned short q1 = (unsigned short)(u >> 16);
        float r1 = f - __uint_as_float(u & 0xffff0000u);
        unsigned u1 = __float_as_uint(r1);
        unsigned short q2 = (unsigned short)(u1 >> 16);
        float r2 = r1 - __uint_as_float(u1 & 0xffff0000u);
        unsigned short q3 = (unsigned short)(__float_as_uint(r2) >> 16);
        a1[j] = q1;
        a2[j] = q2;
        a3[j] = q3;
      }
      *(u16x8*)&h1[row][seg + 8 * g] = a1;
      *(u16x8*)&h2[row][seg + 8 * g] = a2;
      *(u16x8*)&h3[row][seg + 8 * g] = a3;
    }
    __syncthreads();
#pragma unroll
    for (int ks = 0; ks < KCH / 16; ++ks) {
      const int kk = ks * 16 + koff;
      bf16x8 A1 = *(const bf16x8*)&h1[mrow][kk];
      bf16x8 A2 = *(const bf16x8*)&h2[mrow][kk];
      bf16x8 A3 = *(const bf16x8*)&h3[mrow][kk];
      bf16x8 B1 = *(const bf16x8*)&h1[ncol][kk];
      bf16x8 B2 = *(const bf16x8*)&h2[ncol][kk];
      bf16x8 B3 = *(const bf16x8*)&h3[ncol][kk];
      acc = __builtin_amdgcn_mfma_f32_32x32x16_bf16(A1, B1, acc, 0, 0, 0);
      acc = __builtin_amdgcn_mfma_f32_32x32x16_bf16(A1, B2, acc, 0, 0, 0);
      acc = __builtin_amdgcn_mfma_f32_32x32x16_bf16(A2, B1, acc, 0, 0, 0);
      acc = __builtin_amdgcn_mfma_f32_32x32x16_bf16(A2, B2, acc, 0, 0, 0);
      acc = __builtin_amdgcn_mfma_f32_32x32x16_bf16(A1, B3, acc, 0, 0, 0);
      acc = __builtin_amdgcn_mfma_f32_32x32x16_bf16(A3, B1, acc, 0, 0, 0);
    }
    __syncthreads();
  }
  // C/D: col=lane&31, row=(reg&3)+8*(reg>>2)+4*(lane>>5)  [HW-verified]
  float* gp = Gpart + ((size_t)(b * SLICES + s)) * 4096;
#pragma unroll
  for (int r = 0; r < 16; ++r) {
    int row32 = (r & 3) + 8 * (r >> 2) + 4 * (lane >> 5);
    gp[(32 * rw + row32) * 64 + 32 * cw + (lane & 31)] = acc[r];
  }
  rred[row][tid & 3] = rsum;
  __syncthreads();
  if (tid < 64) {
    rspart[((size_t)(b * SLICES + s)) * 64 + tid] =
        rred[tid][0] + rred[tid][1] + rred[tid][2] + rred[tid][3];
  }
}

// ---------------- K2: fp64 reduce partials -> cov (f32), mu, rho/clip ----------------
__global__ __launch_bounds__(256) void k2_reduce(const float* __restrict__ Gpart,
                                                 const float* __restrict__ rspart,
                                                 float* __restrict__ cov32,
                                                 float* __restrict__ mu32,
                                                 double* __restrict__ scal) {
  __shared__ double muS[64];
  __shared__ double red[256];
  const int tid = threadIdx.x;
  const int b = blockIdx.x;
  if (tid < 64) {
    double r = 0.0;
    for (int s = 0; s < SLICES; ++s) r += (double)rspart[((size_t)(b * SLICES + s)) * 64 + tid];
    double mu = r / (double)MMH;
    muS[tid] = mu;
    mu32[b * 64 + tid] = (float)mu;
  }
  __syncthreads();
  const int base = tid * 16;
  const int i = tid >> 2;
  double g[16];
#pragma unroll
  for (int e = 0; e < 16; ++e) g[e] = 0.0;
  for (int s = 0; s < SLICES; ++s) {
    const float* gp = Gpart + ((size_t)(b * SLICES + s)) * 4096 + base;
#pragma unroll
    for (int q = 0; q < 4; ++q) {
      float4 t = *(const float4*)(gp + 4 * q);
      g[4 * q] += (double)t.x;
      g[4 * q + 1] += (double)t.y;
      g[4 * q + 2] += (double)t.z;
      g[4 * q + 3] += (double)t.w;
    }
  }
  double t1 = 0.0, t2 = 0.0;
#pragma unroll
  for (int e = 0; e < 16; ++e) {
    int j = (base + e) & 63;
    double cv = g[e] / (double)MMH - muS[i] * muS[j];
    cov32[(size_t)b * 4096 + base + e] = (float)cv;
    if (i == j) t1 += cv;
    t2 += cv * cv;
  }
  red[tid] = t1;
  __syncthreads();
  for (int st = 128; st > 0; st >>= 1) {
    if (tid < st) red[tid] += red[tid + st];
    __syncthreads();
  }
  double T1 = red[0];
  __syncthreads();
  red[tid] = t2;
  __syncthreads();
  for (int st = 128; st > 0; st >>= 1) {
    if (tid < st) red[tid] += red[tid + st];
    __syncthreads();
  }
  double T2 = red[0];
  if (tid == 0) {
    double num = ((double)(MMH - 2) / (double)MMH) * T2 + T1 * T1;
    double den = (double)(MMH + 2) * (T2 - T1 * T1 / (double)CCH);
    double r = num / den;
    double rho = (r < 1.0) ? r : 1.0;
    scal[b * 4 + 0] = rho;
    scal[b * 4 + 1] = T1 / (double)CCH;
    scal[b * 4 + 2] = 1.0 - rho;
    scal[b * 4 + 3] = (r >= 1.0) ? 1.0 : 0.0;
  }
}

// ---------------- K3: two concurrent roles per batch ----------------
// role 0: Newton-Schulz X=T^{-1/2} (4 iters) -> SxG = X*invsqc, smuA = invsqc*X*mu
// role 1: repeated squaring of sigma*I - A -> v63 (normalized), w, v'mu
__device__ __forceinline__ void gemm_acc(const float (*A)[64], const float (*B)[64],
                                         int i0, int j0, float acc[4][4]) {
#pragma unroll
  for (int a = 0; a < 4; ++a)
#pragma unroll
    for (int c = 0; c < 4; ++c) acc[a][c] = 0.f;
#pragma unroll 4
  for (int k = 0; k < 64; ++k) {
    const float4 av = *(const float4*)&A[k][i0];
    const float4 bv = *(const float4*)&B[k][j0];
    const float aa[4] = {av.x, av.y, av.z, av.w};
    const float bb[4] = {bv.x, bv.y, bv.z, bv.w};
#pragma unroll
    for (int a = 0; a < 4; ++a)
#pragma unroll
      for (int c = 0; c < 4; ++c) acc[a][c] = fmaf(aa[a], bb[c], acc[a][c]);
  }
}

__global__ __launch_bounds__(256) void k3_eig(const float* __restrict__ cov32,
                                              const double* __restrict__ scal,
                                              const float* __restrict__ mu32,
                                              float* __restrict__ SxG,
                                              float* __restrict__ smuA,
                                              float* __restrict__ vS,
                                              float* __restrict__ wvm) {
  __shared__ float As[64][64];
  __shared__ float Xs[64][64];
  __shared__ float Bs[64][64];
  __shared__ float red[64];
  __shared__ float vSh[64];
  __shared__ float ySh[64];
  __shared__ float muS[64];
  const int tid = threadIdx.x;
  const int b = blockIdx.x & 63;
  const int role = blockIdx.x >> 6;
  const double rho = scal[b * 4 + 0];
  const double alpha0 = scal[b * 4 + 1];
  const int clipped = (scal[b * 4 + 3] != 0.0);
  const float invsqc = (float)(1.0 / sqrt(alpha0 + EPSV));
  const int i0 = (tid >> 4) << 2, j0 = (tid & 15) << 2;
  float acc[4][4];
  if (tid < 64) muS[tid] = mu32[b * 64 + tid];

  if (role == 0) {
    if (clipped) {
      for (int k = tid; k < 4096; k += 256) {
        int i = k >> 6, j = k & 63;
        SxG[(size_t)b * 4096 + k] = (i == j) ? invsqc : 0.f;
      }
      if (tid < 64) smuA[b * 64 + tid] = invsqc * muS[tid];
      return;
    }
    const float orhoc = (float)((1.0 - rho) / (alpha0 + EPSV));
    const float dtermc = (float)((rho * alpha0 + EPSV) / (alpha0 + EPSV));
    for (int k = tid; k < 4096; k += 256) {
      int i = k >> 6, j = k & 63;
      float a = cov32[(size_t)b * 4096 + k];
      As[i][j] = a;
      float t = orhoc * a + ((i == j) ? dtermc : 0.f);
      Xs[i][j] = ((i == j) ? 1.5f : 0.f) - 0.5f * t;
    }
    __syncthreads();
    for (int it = 0; it < 4; ++it) {
      gemm_acc(Xs, Xs, i0, j0, acc);  // U = X*X
#pragma unroll
      for (int a = 0; a < 4; ++a)
#pragma unroll
        for (int c = 0; c < 4; ++c) Bs[i0 + a][j0 + c] = acc[a][c];
      __syncthreads();
      gemm_acc(As, Bs, i0, j0, acc);  // A*U
      float bold[4][4];
#pragma unroll
      for (int a = 0; a < 4; ++a)
#pragma unroll
        for (int c = 0; c < 4; ++c) bold[a][c] = Bs[i0 + a][j0 + c];
      __syncthreads();
#pragma unroll
      for (int a = 0; a < 4; ++a)
#pragma unroll
        for (int c = 0; c < 4; ++c) Bs[i0 + a][j0 + c] = orhoc * acc[a][c] + dtermc * bold[a][c];
      __syncthreads();
      gemm_acc(Xs, Bs, i0, j0, acc);  // X*V
      float xold[4][4];
#pragma unroll
      for (int a = 0; a < 4; ++a)
#pragma unroll
        for (int c = 0; c < 4; ++c) xold[a][c] = Xs[i0 + a][j0 + c];
      __syncthreads();
#pragma unroll
      for (int a = 0; a < 4; ++a)
#pragma unroll
        for (int c = 0; c < 4; ++c) Xs[i0 + a][j0 + c] = 1.5f * xold[a][c] - 0.5f * acc[a][c];
      __syncthreads();
    }
    for (int k = tid; k < 4096; k += 256) SxG[(size_t)b * 4096 + k] = Xs[k >> 6][k & 63] * invsqc;
    if (tid < 64) {
      float sm = 0.f;
      for (int j = 0; j < 64; ++j) sm += Xs[j][tid] * muS[j];  // X sym
      smuA[b * 64 + tid] = sm * invsqc;
    }
  } else {
    if (clipped) {
      if (tid < 64) vS[b * 64 + tid] = (tid == 63) ? 1.f : 0.f;
      if (tid == 0) {
        wvm[b * 2] = invsqc;
        wvm[b * 2 + 1] = mu32[b * 64 + 63];
      }
      return;
    }
    for (int k = tid; k < 4096; k += 256) As[k >> 6][k & 63] = cov32[(size_t)b * 4096 + k];
    __syncthreads();
    if (tid < 64) {
      float s = 0.f;
      for (int j = 0; j < 64; ++j) {
        float v = As[j][tid];
        s += (j == tid) ? v : fabsf(v);
      }
      red[tid] = s;
    }
    __syncthreads();
    float sig = 0.f;
    for (int j = 0; j < 64; ++j) sig = fmaxf(sig, red[j]);
    __syncthreads();
#pragma unroll
    for (int a = 0; a < 4; ++a)
#pragma unroll
      for (int c = 0; c < 4; ++c) {
        int i = i0 + a, j = j0 + c;
        Bs[i][j] = ((i == j) ? sig : 0.f) - As[i][j];
      }
    if (i0 == j0)
      red[tid >> 4] = Bs[i0][j0] + Bs[i0 + 1][j0 + 1] + Bs[i0 + 2][j0 + 2] + Bs[i0 + 3][j0 + 3];
    __syncthreads();
    for (int s5 = 0; s5 < 18; ++s5) {
      float t = 0.f;
      for (int j = 0; j < 16; ++j) t += red[j];
      float scale = 1.f / (t * t);
      gemm_acc(Bs, Bs, i0, j0, acc);
      __syncthreads();
#pragma unroll
      for (int a = 0; a < 4; ++a)
#pragma unroll
        for (int c = 0; c < 4; ++c) Bs[i0 + a][j0 + c] = acc[a][c] * scale;
      if (i0 == j0)
        red[tid >> 4] = (acc[0][0] + acc[1][1] + acc[2][2] + acc[3][3]) * scale;
      __syncthreads();
    }
    int jstar = 0;
    float best = -1.f;
    for (int j = 0; j < 64; ++j) {
      float d = Bs[j][j];
      if (d > best) {
        best = d;
        jstar = j;
      }
    }
    if (tid < 64) vSh[tid] = Bs[jstar][tid];
    __syncthreads();
    if (tid < 64) {
      float s = 0.f;
      for (int j = 0; j < 64; ++j) s += As[j][tid] * vSh[j];  // A sym
      ySh[tid] = s;
    }
    __syncthreads();
    float vy = 0.f, vv = 0.f;
    for (int j = 0; j < 64; ++j) {
      vy += vSh[j] * ySh[j];
      vv += vSh[j] * vSh[j];
    }
    float lam = vy / vv;
    float lampr = (float)(rho * alpha0 + EPSV) + (float)(1.0 - rho) * lam;
    float w = 1.f / sqrtf(lampr);
    float invn = 1.f / sqrtf(vv);
    if (tid < 64) vS[b * 64 + tid] = vSh[tid] * invn;
    if (tid == 0) {
      float vmu = 0.f;
      for (int j = 0; j < 64; ++j) vmu += vSh[j] * invn * muS[j];
      wvm[b * 2] = w;
      wvm[b * 2 + 1] = vmu;
    }
  }
}

// ---------------- K7: Z = (SxG - w v v^T) x - smu 1^T  (rank-1 folded in) ----------------
// 128 threads/block, 8x8 per-thread tiles: 4 ds_read_b128 feed 64 FMAs
// (1.0 B/FMA vs 1.5 before) -> LDS-return traffic is no longer the CU
// bottleneck. xsv rows padded to 196 floats (196%32=4) so staging WRITES
// spread across banks (192%32=0 put all rows on the same bank group); the
// in-row 12-float chunk layout (read path) is unchanged.
__global__ __launch_bounds__(128) void k7_z(const float* __restrict__ x,
                                            const float* __restrict__ SxG,
                                            const float* __restrict__ smuA,
                                            const float* __restrict__ vS,
                                            const float* __restrict__ wvm,
                                            float* __restrict__ z) {
  __shared__ float Ss[64][68];
  __shared__ float xsv[64][196];  // 16 chunks of 12 floats (8 used)
  __shared__ float vsh[64];
  __shared__ float smsh[64];
  const int tid = threadIdx.x;  // 0..127
  const int b = blockIdx.y;
  const int t0 = blockIdx.x * TMZ;
  {
    const float* sp = SxG + (size_t)b * 4096 + tid * 32;
    int i = tid >> 1, js = (tid & 1) * 32;
#pragma unroll
    for (int q = 0; q < 8; ++q) *(float4*)&Ss[i][js + 4 * q] = *(const float4*)(sp + 4 * q);
  }
  if (tid < 64) vsh[tid] = vS[b * 64 + tid];
  const float* xb = x + (size_t)b * CCH * MMH + t0;
  {
    int r = tid >> 1, cs = (tid & 1) * 64;
#pragma unroll
    for (int q = 0; q < 8; ++q) {
      int c = cs + q * 8;
      float4 p0 = *(const float4*)(xb + (size_t)r * MMH + c);
      float4 p1 = *(const float4*)(xb + (size_t)r * MMH + c + 4);
      int tcq = c >> 3;
      *(float4*)&xsv[r][12 * tcq] = p0;
      *(float4*)&xsv[r][12 * tcq + 4] = p1;
    }
  }
  __syncthreads();
  const float w = wvm[b * 2], vmu = wvm[b * 2 + 1];
  {
    int i = tid >> 1, js = (tid & 1) * 32;
    float wvi = w * vsh[i];
#pragma unroll
    for (int e = 0; e < 32; ++e) Ss[i][js + e] -= wvi * vsh[js + e];
  }
  if (tid < 64) smsh[tid] = smuA[b * 64 + tid] - w * vsh[tid] * vmu;
  __syncthreads();
  const int tr = tid >> 4, tc = tid & 15;  // tr 0..7, tc 0..15
  const int i0 = tr * 8;
  float acc[8][8];
#pragma unroll
  for (int i = 0; i < 8; ++i)
#pragma unroll
    for (int j = 0; j < 8; ++j) acc[i][j] = 0.f;
#pragma unroll 2
  for (int k = 0; k < 64; ++k) {
    float4 s0 = *(const float4*)&Ss[k][i0];  // S column slice (symmetric)
    float4 s1 = *(const float4*)&Ss[k][i0 + 4];
    float4 xa = *(const float4*)&xsv[k][12 * tc];
    float4 xc = *(const float4*)&xsv[k][12 * tc + 4];
    const float sa[8] = {s0.x, s0.y, s0.z, s0.w, s1.x, s1.y, s1.z, s1.w};
    const float xv[8] = {xa.x, xa.y, xa.z, xa.w, xc.x, xc.y, xc.z, xc.w};
#pragma unroll
    for (int i = 0; i < 8; ++i)
#pragma unroll
      for (int j = 0; j < 8; ++j) acc[i][j] = fmaf(sa[i], xv[j], acc[i][j]);
  }
#pragma unroll
  for (int i = 0; i < 8; ++i) {
    float sm = smsh[i0 + i];
    float4 o0 = make_float4(acc[i][0] - sm, acc[i][1] - sm, acc[i][2] - sm, acc[i][3] - sm);
    float4 o1 = make_float4(acc[i][4] - sm, acc[i][5] - sm, acc[i][6] - sm, acc[i][7] - sm);
    float4* zp = (float4*)(z + ((size_t)b * CCH + i0 + i) * MMH + t0 + tc * 8);
    zp[0] = o0;
    zp[1] = o1;
  }
}

extern "C" void kernel_launch(void* const* d_in, const int* in_sizes, int n_in,
                              void* d_out, int out_size, void* d_ws, size_t ws_size,
                              hipStream_t stream) {
  (void)in_sizes;
  (void)n_in;
  (void)out_size;
  (void)ws_size;
  const float* x = (const float*)d_in[0];
  float* z = (float*)d_out;
  // Gram partials live inside d_out (8.5 MB << 128 MB); overwritten by Z in K7.
  float* Gpart = (float*)d_out;                          // 64*8*4096*4 = 8,388,608
  float* rspart = (float*)((char*)d_out + 8388608);      // 64*8*64*4   = 131,072
  char* ws = (char*)d_ws;
  float* cov32 = (float*)(ws + 0);         // 1,048,576
  float* mu32 = (float*)(ws + 1048576);    // 16,384
  double* scal = (double*)(ws + 1064960);  // 2,048
  float* SxG = (float*)(ws + 1067008);     // 1,048,576
  float* smuA = (float*)(ws + 2115584);    // 16,384
  float* vS = (float*)(ws + 2131968);      // 16,384
  float* wvm = (float*)(ws + 2148352);     // 512

  k1_partG<<<dim3(BB * SLICES), dim3(256), 0, stream>>>(x, Gpart, rspart);
  k2_reduce<<<dim3(BB), dim3(256), 0, stream>>>(Gpart, rspart, cov32, mu32, scal);
  k3_eig<<<dim3(2 * BB), dim3(256), 0, stream>>>(cov32, scal, mu32, SxG, smuA, vS, wvm);
  k7_z<<<dim3(MMH / TMZ, BB), dim3(128), 0, stream>>>(x, SxG, smuA, vS, wvm, z);
}

// Round 3
// 338.694 us; speedup vs baseline: 1.0845x; 1.0845x over previous
//
#include <hip/hip_runtime.h>
#include <math.h>

#define BB 64
#define CCH 64
#define MMH 8192
#define SLICES 8
#define KSL 1024 /* K per k1 block */
#define KCH 128  /* K per LDS chunk in k1 */
#define TMZ 64
constexpr double EPSV = 1e-5;

typedef __attribute__((ext_vector_type(8))) short bf16x8;
typedef __attribute__((ext_vector_type(8))) unsigned short u16x8;
typedef __attribute__((ext_vector_type(16))) float floatx16;

// ---------------- K1: bf16-split MFMA partial Gram + row sums ----------------
// Exact truncation split: x = t1+t2+t3 BIT-EXACT (24-bit fp32 mantissa = 3x8
// bf16 significands; bf16 exponent range == fp32 so no underflow).
// G = 6 split products via mfma_f32_32x32x16_bf16, fp32 accum;
// dropped cross terms t2t3/t3t2/t3t3 ~ 2^-40 rel.
__global__ __launch_bounds__(256, 2) void k1_partG(const float* __restrict__ x,
                                                   float* __restrict__ Gpart,
                                                   float* __restrict__ rspart) {
  __shared__ unsigned short h1[64][KCH + 8], h2[64][KCH + 8], h3[64][KCH + 8];
  __shared__ float rred[64][4];
  const int tid = threadIdx.x;
  const int b = blockIdx.x / SLICES;
  const int s = blockIdx.x % SLICES;
  const int row = tid >> 2;
  const int seg = (tid & 3) * 32;
  const int wv = tid >> 6;
  const int lane = tid & 63;
  const int rw = wv >> 1, cw = wv & 1;
  const int mrow = 32 * rw + (lane & 31);
  const int ncol = 32 * cw + (lane & 31);
  const int koff = (lane >> 5) * 8;
  const float* xb = x + (size_t)b * CCH * MMH + (size_t)s * KSL;
  floatx16 acc = {};
  float rsum = 0.f;
  for (int c = 0; c < KSL / KCH; ++c) {
    const float* xp = xb + (size_t)row * MMH + c * KCH + seg;
    float v[32];
#pragma unroll
    for (int q = 0; q < 8; ++q) {
      float4 t = *(const float4*)(xp + 4 * q);
      v[4 * q] = t.x;
      v[4 * q + 1] = t.y;
      v[4 * q + 2] = t.z;
      v[4 * q + 3] = t.w;
    }
#pragma unroll
    for (int o = 0; o < 32; ++o) rsum += v[o];
#pragma unroll
    for (int g = 0; g < 4; ++g) {
      u16x8 a1, a2, a3;
#pragma unroll
      for (int j = 0; j < 8; ++j) {
        float f = v[8 * g + j];
        unsigned u = __float_as_uint(f);
        unsigned short q1 = (unsigned short)(u >> 16);
        float r1 = f - __uint_as_float(u & 0xffff0000u);
        unsigned u1 = __float_as_uint(r1);
        unsigned short q2 = (unsigned short)(u1 >> 16);
        float r2 = r1 - __uint_as_float(u1 & 0xffff0000u);
        unsigned short q3 = (unsigned short)(__float_as_uint(r2) >> 16);
        a1[j] = q1;
        a2[j] = q2;
        a3[j] = q3;
      }
      *(u16x8*)&h1[row][seg + 8 * g] = a1;
      *(u16x8*)&h2[row][seg + 8 * g] = a2;
      *(u16x8*)&h3[row][seg + 8 * g] = a3;
    }
    __syncthreads();
#pragma unroll
    for (int ks = 0; ks < KCH / 16; ++ks) {
      const int kk = ks * 16 + koff;
      bf16x8 A1 = *(const bf16x8*)&h1[mrow][kk];
      bf16x8 A2 = *(const bf16x8*)&h2[mrow][kk];
      bf16x8 A3 = *(const bf16x8*)&h3[mrow][kk];
      bf16x8 B1 = *(const bf16x8*)&h1[ncol][kk];
      bf16x8 B2 = *(const bf16x8*)&h2[ncol][kk];
      bf16x8 B3 = *(const bf16x8*)&h3[ncol][kk];
      acc = __builtin_amdgcn_mfma_f32_32x32x16_bf16(A1, B1, acc, 0, 0, 0);
      acc = __builtin_amdgcn_mfma_f32_32x32x16_bf16(A1, B2, acc, 0, 0, 0);
      acc = __builtin_amdgcn_mfma_f32_32x32x16_bf16(A2, B1, acc, 0, 0, 0);
      acc = __builtin_amdgcn_mfma_f32_32x32x16_bf16(A2, B2, acc, 0, 0, 0);
      acc = __builtin_amdgcn_mfma_f32_32x32x16_bf16(A1, B3, acc, 0, 0, 0);
      acc = __builtin_amdgcn_mfma_f32_32x32x16_bf16(A3, B1, acc, 0, 0, 0);
    }
    __syncthreads();
  }
  // C/D: col=lane&31, row=(reg&3)+8*(reg>>2)+4*(lane>>5)  [HW-verified]
  float* gp = Gpart + ((size_t)(b * SLICES + s)) * 4096;
#pragma unroll
  for (int r = 0; r < 16; ++r) {
    int row32 = (r & 3) + 8 * (r >> 2) + 4 * (lane >> 5);
    gp[(32 * rw + row32) * 64 + 32 * cw + (lane & 31)] = acc[r];
  }
  rred[row][tid & 3] = rsum;
  __syncthreads();
  if (tid < 64) {
    rspart[((size_t)(b * SLICES + s)) * 64 + tid] =
        rred[tid][0] + rred[tid][1] + rred[tid][2] + rred[tid][3];
  }
}

// ---------------- K2: fp64 reduce partials -> cov (f32), mu, rho/clip ----------------
__global__ __launch_bounds__(256) void k2_reduce(const float* __restrict__ Gpart,
                                                 const float* __restrict__ rspart,
                                                 float* __restrict__ cov32,
                                                 float* __restrict__ mu32,
                                                 double* __restrict__ scal) {
  __shared__ double muS[64];
  __shared__ double red[256];
  const int tid = threadIdx.x;
  const int b = blockIdx.x;
  if (tid < 64) {
    double r = 0.0;
    for (int s = 0; s < SLICES; ++s) r += (double)rspart[((size_t)(b * SLICES + s)) * 64 + tid];
    double mu = r / (double)MMH;
    muS[tid] = mu;
    mu32[b * 64 + tid] = (float)mu;
  }
  __syncthreads();
  const int base = tid * 16;
  const int i = tid >> 2;
  double g[16];
#pragma unroll
  for (int e = 0; e < 16; ++e) g[e] = 0.0;
  for (int s = 0; s < SLICES; ++s) {
    const float* gp = Gpart + ((size_t)(b * SLICES + s)) * 4096 + base;
#pragma unroll
    for (int q = 0; q < 4; ++q) {
      float4 t = *(const float4*)(gp + 4 * q);
      g[4 * q] += (double)t.x;
      g[4 * q + 1] += (double)t.y;
      g[4 * q + 2] += (double)t.z;
      g[4 * q + 3] += (double)t.w;
    }
  }
  double t1 = 0.0, t2 = 0.0;
#pragma unroll
  for (int e = 0; e < 16; ++e) {
    int j = (base + e) & 63;
    double cv = g[e] / (double)MMH - muS[i] * muS[j];
    cov32[(size_t)b * 4096 + base + e] = (float)cv;
    if (i == j) t1 += cv;
    t2 += cv * cv;
  }
  red[tid] = t1;
  __syncthreads();
  for (int st = 128; st > 0; st >>= 1) {
    if (tid < st) red[tid] += red[tid + st];
    __syncthreads();
  }
  double T1 = red[0];
  __syncthreads();
  red[tid] = t2;
  __syncthreads();
  for (int st = 128; st > 0; st >>= 1) {
    if (tid < st) red[tid] += red[tid + st];
    __syncthreads();
  }
  double T2 = red[0];
  if (tid == 0) {
    double num = ((double)(MMH - 2) / (double)MMH) * T2 + T1 * T1;
    double den = (double)(MMH + 2) * (T2 - T1 * T1 / (double)CCH);
    double r = num / den;
    double rho = (r < 1.0) ? r : 1.0;
    scal[b * 4 + 0] = rho;
    scal[b * 4 + 1] = T1 / (double)CCH;
    scal[b * 4 + 2] = 1.0 - rho;
    scal[b * 4 + 3] = (r >= 1.0) ? 1.0 : 0.0;
  }
}

// ---------------- K3: two concurrent roles per batch ----------------
// role 0: Newton-Schulz X=T^{-1/2} (4 iters) -> SxG = X*invsqc, smuA = invsqc*X*mu
// role 1: repeated squaring of sigma*I - A -> v63 (normalized), w, v'mu
__device__ __forceinline__ void gemm_acc(const float (*A)[64], const float (*B)[64],
                                         int i0, int j0, float acc[4][4]) {
#pragma unroll
  for (int a = 0; a < 4; ++a)
#pragma unroll
    for (int c = 0; c < 4; ++c) acc[a][c] = 0.f;
#pragma unroll 4
  for (int k = 0; k < 64; ++k) {
    const float4 av = *(const float4*)&A[k][i0];
    const float4 bv = *(const float4*)&B[k][j0];
    const float aa[4] = {av.x, av.y, av.z, av.w};
    const float bb[4] = {bv.x, bv.y, bv.z, bv.w};
#pragma unroll
    for (int a = 0; a < 4; ++a)
#pragma unroll
      for (int c = 0; c < 4; ++c) acc[a][c] = fmaf(aa[a], bb[c], acc[a][c]);
  }
}

__global__ __launch_bounds__(256) void k3_eig(const float* __restrict__ cov32,
                                              const double* __restrict__ scal,
                                              const float* __restrict__ mu32,
                                              float* __restrict__ SxG,
                                              float* __restrict__ smuA,
                                              float* __restrict__ vS,
                                              float* __restrict__ wvm) {
  __shared__ float As[64][64];
  __shared__ float Xs[64][64];
  __shared__ float Bs[64][64];
  __shared__ float red[64];
  __shared__ float vSh[64];
  __shared__ float ySh[64];
  __shared__ float muS[64];
  const int tid = threadIdx.x;
  const int b = blockIdx.x & 63;
  const int role = blockIdx.x >> 6;
  const double rho = scal[b * 4 + 0];
  const double alpha0 = scal[b * 4 + 1];
  const int clipped = (scal[b * 4 + 3] != 0.0);
  const float invsqc = (float)(1.0 / sqrt(alpha0 + EPSV));
  const int i0 = (tid >> 4) << 2, j0 = (tid & 15) << 2;
  float acc[4][4];
  if (tid < 64) muS[tid] = mu32[b * 64 + tid];

  if (role == 0) {
    if (clipped) {
      for (int k = tid; k < 4096; k += 256) {
        int i = k >> 6, j = k & 63;
        SxG[(size_t)b * 4096 + k] = (i == j) ? invsqc : 0.f;
      }
      if (tid < 64) smuA[b * 64 + tid] = invsqc * muS[tid];
      return;
    }
    const float orhoc = (float)((1.0 - rho) / (alpha0 + EPSV));
    const float dtermc = (float)((rho * alpha0 + EPSV) / (alpha0 + EPSV));
    for (int k = tid; k < 4096; k += 256) {
      int i = k >> 6, j = k & 63;
      float a = cov32[(size_t)b * 4096 + k];
      As[i][j] = a;
      float t = orhoc * a + ((i == j) ? dtermc : 0.f);
      Xs[i][j] = ((i == j) ? 1.5f : 0.f) - 0.5f * t;
    }
    __syncthreads();
    for (int it = 0; it < 4; ++it) {
      gemm_acc(Xs, Xs, i0, j0, acc);  // U = X*X
#pragma unroll
      for (int a = 0; a < 4; ++a)
#pragma unroll
        for (int c = 0; c < 4; ++c) Bs[i0 + a][j0 + c] = acc[a][c];
      __syncthreads();
      gemm_acc(As, Bs, i0, j0, acc);  // A*U
      float bold[4][4];
#pragma unroll
      for (int a = 0; a < 4; ++a)
#pragma unroll
        for (int c = 0; c < 4; ++c) bold[a][c] = Bs[i0 + a][j0 + c];
      __syncthreads();
#pragma unroll
      for (int a = 0; a < 4; ++a)
#pragma unroll
        for (int c = 0; c < 4; ++c) Bs[i0 + a][j0 + c] = orhoc * acc[a][c] + dtermc * bold[a][c];
      __syncthreads();
      gemm_acc(Xs, Bs, i0, j0, acc);  // X*V
      float xold[4][4];
#pragma unroll
      for (int a = 0; a < 4; ++a)
#pragma unroll
        for (int c = 0; c < 4; ++c) xold[a][c] = Xs[i0 + a][j0 + c];
      __syncthreads();
#pragma unroll
      for (int a = 0; a < 4; ++a)
#pragma unroll
        for (int c = 0; c < 4; ++c) Xs[i0 + a][j0 + c] = 1.5f * xold[a][c] - 0.5f * acc[a][c];
      __syncthreads();
    }
    for (int k = tid; k < 4096; k += 256) SxG[(size_t)b * 4096 + k] = Xs[k >> 6][k & 63] * invsqc;
    if (tid < 64) {
      float sm = 0.f;
      for (int j = 0; j < 64; ++j) sm += Xs[j][tid] * muS[j];  // X sym
      smuA[b * 64 + tid] = sm * invsqc;
    }
  } else {
    if (clipped) {
      if (tid < 64) vS[b * 64 + tid] = (tid == 63) ? 1.f : 0.f;
      if (tid == 0) {
        wvm[b * 2] = invsqc;
        wvm[b * 2 + 1] = mu32[b * 64 + 63];
      }
      return;
    }
    for (int k = tid; k < 4096; k += 256) As[k >> 6][k & 63] = cov32[(size_t)b * 4096 + k];
    __syncthreads();
    if (tid < 64) {
      float s = 0.f;
      for (int j = 0; j < 64; ++j) {
        float v = As[j][tid];
        s += (j == tid) ? v : fabsf(v);
      }
      red[tid] = s;
    }
    __syncthreads();
    float sig = 0.f;
    for (int j = 0; j < 64; ++j) sig = fmaxf(sig, red[j]);
    __syncthreads();
#pragma unroll
    for (int a = 0; a < 4; ++a)
#pragma unroll
      for (int c = 0; c < 4; ++c) {
        int i = i0 + a, j = j0 + c;
        Bs[i][j] = ((i == j) ? sig : 0.f) - As[i][j];
      }
    if (i0 == j0)
      red[tid >> 4] = Bs[i0][j0] + Bs[i0 + 1][j0 + 1] + Bs[i0 + 2][j0 + 2] + Bs[i0 + 3][j0 + 3];
    __syncthreads();
    for (int s5 = 0; s5 < 18; ++s5) {
      float t = 0.f;
      for (int j = 0; j < 16; ++j) t += red[j];
      float scale = 1.f / (t * t);
      gemm_acc(Bs, Bs, i0, j0, acc);
      __syncthreads();
#pragma unroll
      for (int a = 0; a < 4; ++a)
#pragma unroll
        for (int c = 0; c < 4; ++c) Bs[i0 + a][j0 + c] = acc[a][c] * scale;
      if (i0 == j0)
        red[tid >> 4] = (acc[0][0] + acc[1][1] + acc[2][2] + acc[3][3]) * scale;
      __syncthreads();
    }
    int jstar = 0;
    float best = -1.f;
    for (int j = 0; j < 64; ++j) {
      float d = Bs[j][j];
      if (d > best) {
        best = d;
        jstar = j;
      }
    }
    if (tid < 64) vSh[tid] = Bs[jstar][tid];
    __syncthreads();
    if (tid < 64) {
      float s = 0.f;
      for (int j = 0; j < 64; ++j) s += As[j][tid] * vSh[j];  // A sym
      ySh[tid] = s;
    }
    __syncthreads();
    float vy = 0.f, vv = 0.f;
    for (int j = 0; j < 64; ++j) {
      vy += vSh[j] * ySh[j];
      vv += vSh[j] * vSh[j];
    }
    float lam = vy / vv;
    float lampr = (float)(rho * alpha0 + EPSV) + (float)(1.0 - rho) * lam;
    float w = 1.f / sqrtf(lampr);
    float invn = 1.f / sqrtf(vv);
    if (tid < 64) vS[b * 64 + tid] = vSh[tid] * invn;
    if (tid == 0) {
      float vmu = 0.f;
      for (int j = 0; j < 64; ++j) vmu += vSh[j] * invn * muS[j];
      wvm[b * 2] = w;
      wvm[b * 2 + 1] = vmu;
    }
  }
}

// ---------------- K7: Z = (SxG - w v v^T) x - smu 1^T  (rank-1 folded in) ----------------
// Occupancy-first redesign: 256 thr, TMZ=64, 8 rows x 2 cols per thread.
// LDS = Ss[64][68] (17.4K) + xsv[64][64] rotate-swizzled (16.4K) + 0.5K
//     = 34.3 KB -> 4 blocks/CU = 16 waves/CU (50% occupancy).
// Per k: 2 broadcast ds_read_b128 (S; 2 distinct addrs/wave = free) +
// 1 ds_read_b64 (x; rotate swizzle (chunk+k)&31 -> 16 banks 2-way = free)
// feeding 16 FMAs -> VALU-bound inner loop with latency well hidden.
__global__ __launch_bounds__(256, 4) void k7_z(const float* __restrict__ x,
                                               const float* __restrict__ SxG,
                                               const float* __restrict__ smuA,
                                               const float* __restrict__ vS,
                                               const float* __restrict__ wvm,
                                               float* __restrict__ z) {
  __shared__ float Ss[64][68];
  __shared__ float xsv[64][64];  // row k, chunk c (2 floats) at ((c + k) & 31) * 2
  __shared__ float vsh[64];
  __shared__ float smsh[64];
  const int tid = threadIdx.x;
  const int b = blockIdx.y;
  const int t0 = blockIdx.x * TMZ;
  {
    const float* sp = SxG + (size_t)b * 4096 + tid * 16;
    int i = tid >> 2, js = (tid & 3) * 16;
#pragma unroll
    for (int q = 0; q < 4; ++q) *(float4*)&Ss[i][js + 4 * q] = *(const float4*)(sp + 4 * q);
  }
  if (tid < 64) vsh[tid] = vS[b * 64 + tid];
  const float* xb = x + (size_t)b * CCH * MMH + t0;
  {
// 1024 float4 tile loads; quarter-wave covers one full 256 B row segment
#pragma unroll
    for (int q = 0; q < 4; ++q) {
      int id = q * 256 + tid;
      int r = id >> 4, c4 = id & 15;
      float4 v = *(const float4*)(xb + (size_t)r * MMH + 4 * c4);
      int p0 = ((2 * c4 + r) & 31) * 2;
      int p1 = ((2 * c4 + 1 + r) & 31) * 2;
      *(float2*)&xsv[r][p0] = make_float2(v.x, v.y);
      *(float2*)&xsv[r][p1] = make_float2(v.z, v.w);
    }
  }
  __syncthreads();
  const float w = wvm[b * 2], vmu = wvm[b * 2 + 1];
  {
    int i = tid >> 2, js = (tid & 3) * 16;
    float wvi = w * vsh[i];
#pragma unroll
    for (int e = 0; e < 16; ++e) Ss[i][js + e] -= wvi * vsh[js + e];
  }
  if (tid < 64) smsh[tid] = smuA[b * 64 + tid] - w * vsh[tid] * vmu;
  __syncthreads();
  const int tr = tid >> 5, tc = tid & 31;  // tr 0..7, tc 0..31
  const int i0 = tr * 8;
  float acc[8][2];
#pragma unroll
  for (int i = 0; i < 8; ++i) {
    acc[i][0] = 0.f;
    acc[i][1] = 0.f;
  }
#pragma unroll 4
  for (int k = 0; k < 64; ++k) {
    float4 s0 = *(const float4*)&Ss[k][i0];  // S column slice (symmetric)
    float4 s1 = *(const float4*)&Ss[k][i0 + 4];
    float2 xv = *(const float2*)&xsv[k][((tc + k) & 31) * 2];
    const float sa[8] = {s0.x, s0.y, s0.z, s0.w, s1.x, s1.y, s1.z, s1.w};
#pragma unroll
    for (int i = 0; i < 8; ++i) {
      acc[i][0] = fmaf(sa[i], xv.x, acc[i][0]);
      acc[i][1] = fmaf(sa[i], xv.y, acc[i][1]);
    }
  }
#pragma unroll
  for (int i = 0; i < 8; ++i) {
    float sm = smsh[i0 + i];
    float2 o = make_float2(acc[i][0] - sm, acc[i][1] - sm);
    *(float2*)(z + ((size_t)b * CCH + i0 + i) * MMH + t0 + tc * 2) = o;
  }
}

extern "C" void kernel_launch(void* const* d_in, const int* in_sizes, int n_in,
                              void* d_out, int out_size, void* d_ws, size_t ws_size,
                              hipStream_t stream) {
  (void)in_sizes;
  (void)n_in;
  (void)out_size;
  (void)ws_size;
  const float* x = (const float*)d_in[0];
  float* z = (float*)d_out;
  // Gram partials live inside d_out (8.5 MB << 128 MB); overwritten by Z in K7.
  float* Gpart = (float*)d_out;                          // 64*8*4096*4 = 8,388,608
  float* rspart = (float*)((char*)d_out + 8388608);      // 64*8*64*4   = 131,072
  char* ws = (char*)d_ws;
  float* cov32 = (float*)(ws + 0);         // 1,048,576
  float* mu32 = (float*)(ws + 1048576);    // 16,384
  double* scal = (double*)(ws + 1064960);  // 2,048
  float* SxG = (float*)(ws + 1067008);     // 1,048,576
  float* smuA = (float*)(ws + 2115584);    // 16,384
  float* vS = (float*)(ws + 2131968);      // 16,384
  float* wvm = (float*)(ws + 2148352);     // 512

  k1_partG<<<dim3(BB * SLICES), dim3(256), 0, stream>>>(x, Gpart, rspart);
  k2_reduce<<<dim3(BB), dim3(256), 0, stream>>>(Gpart, rspart, cov32, mu32, scal);
  k3_eig<<<dim3(2 * BB), dim3(256), 0, stream>>>(cov32, scal, mu32, SxG, smuA, vS, wvm);
  k7_z<<<dim3(MMH / TMZ, BB), dim3(256), 0, stream>>>(x, SxG, smuA, vS, wvm, z);
}

// Round 4
// 317.123 us; speedup vs baseline: 1.1582x; 1.0680x over previous
//
#include <hip/hip_runtime.h>
#include <math.h>

#define BB 64
#define CCH 64
#define MMH 8192
#define SLICES 8
#define KSL 1024 /* K per k1 block */
#define KCH 128  /* K per LDS chunk in k1 */
#define TNB 128  /* cols per k7 block */
constexpr double EPSV = 1e-5;

typedef __attribute__((ext_vector_type(8))) short bf16x8;
typedef __attribute__((ext_vector_type(8))) unsigned short u16x8;
typedef __attribute__((ext_vector_type(16))) float floatx16;

// Exact truncation split: f = t1+t2+t3 bit-exact (24-bit mantissa = 3x8 bf16
// significands; bf16 exponent range == fp32 so no underflow).
__device__ __forceinline__ void split3(float f, unsigned short& q1, unsigned short& q2,
                                       unsigned short& q3) {
  unsigned u = __float_as_uint(f);
  q1 = (unsigned short)(u >> 16);
  float r1 = f - __uint_as_float(u & 0xffff0000u);
  unsigned u1 = __float_as_uint(r1);
  q2 = (unsigned short)(u1 >> 16);
  float r2 = r1 - __uint_as_float(u1 & 0xffff0000u);
  q3 = (unsigned short)(__float_as_uint(r2) >> 16);
}

// ---------------- K1: bf16-split MFMA partial Gram + row sums ----------------
// G = 6 split products via mfma_f32_32x32x16_bf16, fp32 accum;
// dropped cross terms ~2^-24..2^-32 rel.
__global__ __launch_bounds__(256, 3) void k1_partG(const float* __restrict__ x,
                                                   float* __restrict__ Gpart,
                                                   float* __restrict__ rspart) {
  __shared__ unsigned short h1[64][KCH + 8], h2[64][KCH + 8], h3[64][KCH + 8];
  __shared__ float rred[64][4];
  const int tid = threadIdx.x;
  const int b = blockIdx.x / SLICES;
  const int s = blockIdx.x % SLICES;
  const int row = tid >> 2;
  const int seg = (tid & 3) * 32;
  const int wv = tid >> 6;
  const int lane = tid & 63;
  const int rw = wv >> 1, cw = wv & 1;
  const int mrow = 32 * rw + (lane & 31);
  const int ncol = 32 * cw + (lane & 31);
  const int koff = (lane >> 5) * 8;
  const float* xb = x + (size_t)b * CCH * MMH + (size_t)s * KSL;
  floatx16 acc = {};
  float rsum = 0.f;
  for (int c = 0; c < KSL / KCH; ++c) {
    const float* xp = xb + (size_t)row * MMH + c * KCH + seg;
    float v[32];
#pragma unroll
    for (int q = 0; q < 8; ++q) {
      float4 t = *(const float4*)(xp + 4 * q);
      v[4 * q] = t.x;
      v[4 * q + 1] = t.y;
      v[4 * q + 2] = t.z;
      v[4 * q + 3] = t.w;
    }
#pragma unroll
    for (int o = 0; o < 32; ++o) rsum += v[o];
#pragma unroll
    for (int g = 0; g < 4; ++g) {
      u16x8 a1, a2, a3;
#pragma unroll
      for (int j = 0; j < 8; ++j) {
        unsigned short q1, q2, q3;
        split3(v[8 * g + j], q1, q2, q3);
        a1[j] = q1;
        a2[j] = q2;
        a3[j] = q3;
      }
      *(u16x8*)&h1[row][seg + 8 * g] = a1;
      *(u16x8*)&h2[row][seg + 8 * g] = a2;
      *(u16x8*)&h3[row][seg + 8 * g] = a3;
    }
    __syncthreads();
#pragma unroll
    for (int ks = 0; ks < KCH / 16; ++ks) {
      const int kk = ks * 16 + koff;
      bf16x8 A1 = *(const bf16x8*)&h1[mrow][kk];
      bf16x8 A2 = *(const bf16x8*)&h2[mrow][kk];
      bf16x8 A3 = *(const bf16x8*)&h3[mrow][kk];
      bf16x8 B1 = *(const bf16x8*)&h1[ncol][kk];
      bf16x8 B2 = *(const bf16x8*)&h2[ncol][kk];
      bf16x8 B3 = *(const bf16x8*)&h3[ncol][kk];
      acc = __builtin_amdgcn_mfma_f32_32x32x16_bf16(A1, B1, acc, 0, 0, 0);
      acc = __builtin_amdgcn_mfma_f32_32x32x16_bf16(A1, B2, acc, 0, 0, 0);
      acc = __builtin_amdgcn_mfma_f32_32x32x16_bf16(A2, B1, acc, 0, 0, 0);
      acc = __builtin_amdgcn_mfma_f32_32x32x16_bf16(A2, B2, acc, 0, 0, 0);
      acc = __builtin_amdgcn_mfma_f32_32x32x16_bf16(A1, B3, acc, 0, 0, 0);
      acc = __builtin_amdgcn_mfma_f32_32x32x16_bf16(A3, B1, acc, 0, 0, 0);
    }
    __syncthreads();
  }
  // C/D: col=lane&31, row=(reg&3)+8*(reg>>2)+4*(lane>>5)  [HW-verified]
  float* gp = Gpart + ((size_t)(b * SLICES + s)) * 4096;
#pragma unroll
  for (int r = 0; r < 16; ++r) {
    int row32 = (r & 3) + 8 * (r >> 2) + 4 * (lane >> 5);
    gp[(32 * rw + row32) * 64 + 32 * cw + (lane & 31)] = acc[r];
  }
  rred[row][tid & 3] = rsum;
  __syncthreads();
  if (tid < 64) {
    rspart[((size_t)(b * SLICES + s)) * 64 + tid] =
        rred[tid][0] + rred[tid][1] + rred[tid][2] + rred[tid][3];
  }
}

// ---------------- K2: fp64 reduce partials -> cov (f32), mu, rho/clip ----------------
__global__ __launch_bounds__(256) void k2_reduce(const float* __restrict__ Gpart,
                                                 const float* __restrict__ rspart,
                                                 float* __restrict__ cov32,
                                                 float* __restrict__ mu32,
                                                 double* __restrict__ scal) {
  __shared__ double muS[64];
  __shared__ double red[256];
  const int tid = threadIdx.x;
  const int b = blockIdx.x;
  if (tid < 64) {
    double r = 0.0;
    for (int s = 0; s < SLICES; ++s) r += (double)rspart[((size_t)(b * SLICES + s)) * 64 + tid];
    double mu = r / (double)MMH;
    muS[tid] = mu;
    mu32[b * 64 + tid] = (float)mu;
  }
  __syncthreads();
  const int base = tid * 16;
  const int i = tid >> 2;
  double g[16];
#pragma unroll
  for (int e = 0; e < 16; ++e) g[e] = 0.0;
  for (int s = 0; s < SLICES; ++s) {
    const float* gp = Gpart + ((size_t)(b * SLICES + s)) * 4096 + base;
#pragma unroll
    for (int q = 0; q < 4; ++q) {
      float4 t = *(const float4*)(gp + 4 * q);
      g[4 * q] += (double)t.x;
      g[4 * q + 1] += (double)t.y;
      g[4 * q + 2] += (double)t.z;
      g[4 * q + 3] += (double)t.w;
    }
  }
  double t1 = 0.0, t2 = 0.0;
#pragma unroll
  for (int e = 0; e < 16; ++e) {
    int j = (base + e) & 63;
    double cv = g[e] / (double)MMH - muS[i] * muS[j];
    cov32[(size_t)b * 4096 + base + e] = (float)cv;
    if (i == j) t1 += cv;
    t2 += cv * cv;
  }
  red[tid] = t1;
  __syncthreads();
  for (int st = 128; st > 0; st >>= 1) {
    if (tid < st) red[tid] += red[tid + st];
    __syncthreads();
  }
  double T1 = red[0];
  __syncthreads();
  red[tid] = t2;
  __syncthreads();
  for (int st = 128; st > 0; st >>= 1) {
    if (tid < st) red[tid] += red[tid + st];
    __syncthreads();
  }
  double T2 = red[0];
  if (tid == 0) {
    double num = ((double)(MMH - 2) / (double)MMH) * T2 + T1 * T1;
    double den = (double)(MMH + 2) * (T2 - T1 * T1 / (double)CCH);
    double r = num / den;
    double rho = (r < 1.0) ? r : 1.0;
    scal[b * 4 + 0] = rho;
    scal[b * 4 + 1] = T1 / (double)CCH;
    scal[b * 4 + 2] = 1.0 - rho;
    scal[b * 4 + 3] = (r >= 1.0) ? 1.0 : 0.0;
  }
}

// ---------------- K3: two concurrent roles per batch ----------------
// role 0: Newton-Schulz X=T^{-1/2} (4 iters) -> SxG = X*invsqc, smuA = invsqc*X*mu
// role 1: repeated squaring of sigma*I - A -> v63 (normalized), w, v'mu
__device__ __forceinline__ void gemm_acc(const float (*A)[64], const float (*B)[64],
                                         int i0, int j0, float acc[4][4]) {
#pragma unroll
  for (int a = 0; a < 4; ++a)
#pragma unroll
    for (int c = 0; c < 4; ++c) acc[a][c] = 0.f;
#pragma unroll 4
  for (int k = 0; k < 64; ++k) {
    const float4 av = *(const float4*)&A[k][i0];
    const float4 bv = *(const float4*)&B[k][j0];
    const float aa[4] = {av.x, av.y, av.z, av.w};
    const float bb[4] = {bv.x, bv.y, bv.z, bv.w};
#pragma unroll
    for (int a = 0; a < 4; ++a)
#pragma unroll
      for (int c = 0; c < 4; ++c) acc[a][c] = fmaf(aa[a], bb[c], acc[a][c]);
  }
}

__global__ __launch_bounds__(256) void k3_eig(const float* __restrict__ cov32,
                                              const double* __restrict__ scal,
                                              const float* __restrict__ mu32,
                                              float* __restrict__ SxG,
                                              float* __restrict__ smuA,
                                              float* __restrict__ vS,
                                              float* __restrict__ wvm) {
  __shared__ float As[64][64];
  __shared__ float Xs[64][64];
  __shared__ float Bs[64][64];
  __shared__ float red[64];
  __shared__ float vSh[64];
  __shared__ float ySh[64];
  __shared__ float muS[64];
  const int tid = threadIdx.x;
  const int b = blockIdx.x & 63;
  const int role = blockIdx.x >> 6;
  const double rho = scal[b * 4 + 0];
  const double alpha0 = scal[b * 4 + 1];
  const int clipped = (scal[b * 4 + 3] != 0.0);
  const float invsqc = (float)(1.0 / sqrt(alpha0 + EPSV));
  const int i0 = (tid >> 4) << 2, j0 = (tid & 15) << 2;
  float acc[4][4];
  if (tid < 64) muS[tid] = mu32[b * 64 + tid];

  if (role == 0) {
    if (clipped) {
      for (int k = tid; k < 4096; k += 256) {
        int i = k >> 6, j = k & 63;
        SxG[(size_t)b * 4096 + k] = (i == j) ? invsqc : 0.f;
      }
      if (tid < 64) smuA[b * 64 + tid] = invsqc * muS[tid];
      return;
    }
    const float orhoc = (float)((1.0 - rho) / (alpha0 + EPSV));
    const float dtermc = (float)((rho * alpha0 + EPSV) / (alpha0 + EPSV));
    for (int k = tid; k < 4096; k += 256) {
      int i = k >> 6, j = k & 63;
      float a = cov32[(size_t)b * 4096 + k];
      As[i][j] = a;
      float t = orhoc * a + ((i == j) ? dtermc : 0.f);
      Xs[i][j] = ((i == j) ? 1.5f : 0.f) - 0.5f * t;
    }
    __syncthreads();
    for (int it = 0; it < 4; ++it) {
      gemm_acc(Xs, Xs, i0, j0, acc);  // U = X*X
#pragma unroll
      for (int a = 0; a < 4; ++a)
#pragma unroll
        for (int c = 0; c < 4; ++c) Bs[i0 + a][j0 + c] = acc[a][c];
      __syncthreads();
      gemm_acc(As, Bs, i0, j0, acc);  // A*U
      float bold[4][4];
#pragma unroll
      for (int a = 0; a < 4; ++a)
#pragma unroll
        for (int c = 0; c < 4; ++c) bold[a][c] = Bs[i0 + a][j0 + c];
      __syncthreads();
#pragma unroll
      for (int a = 0; a < 4; ++a)
#pragma unroll
        for (int c = 0; c < 4; ++c) Bs[i0 + a][j0 + c] = orhoc * acc[a][c] + dtermc * bold[a][c];
      __syncthreads();
      gemm_acc(Xs, Bs, i0, j0, acc);  // X*V
      float xold[4][4];
#pragma unroll
      for (int a = 0; a < 4; ++a)
#pragma unroll
        for (int c = 0; c < 4; ++c) xold[a][c] = Xs[i0 + a][j0 + c];
      __syncthreads();
#pragma unroll
      for (int a = 0; a < 4; ++a)
#pragma unroll
        for (int c = 0; c < 4; ++c) Xs[i0 + a][j0 + c] = 1.5f * xold[a][c] - 0.5f * acc[a][c];
      __syncthreads();
    }
    for (int k = tid; k < 4096; k += 256) SxG[(size_t)b * 4096 + k] = Xs[k >> 6][k & 63] * invsqc;
    if (tid < 64) {
      float sm = 0.f;
      for (int j = 0; j < 64; ++j) sm += Xs[j][tid] * muS[j];  // X sym
      smuA[b * 64 + tid] = sm * invsqc;
    }
  } else {
    if (clipped) {
      if (tid < 64) vS[b * 64 + tid] = (tid == 63) ? 1.f : 0.f;
      if (tid == 0) {
        wvm[b * 2] = invsqc;
        wvm[b * 2 + 1] = mu32[b * 64 + 63];
      }
      return;
    }
    for (int k = tid; k < 4096; k += 256) As[k >> 6][k & 63] = cov32[(size_t)b * 4096 + k];
    __syncthreads();
    if (tid < 64) {
      float s = 0.f;
      for (int j = 0; j < 64; ++j) {
        float v = As[j][tid];
        s += (j == tid) ? v : fabsf(v);
      }
      red[tid] = s;
    }
    __syncthreads();
    float sig = 0.f;
    for (int j = 0; j < 64; ++j) sig = fmaxf(sig, red[j]);
    __syncthreads();
#pragma unroll
    for (int a = 0; a < 4; ++a)
#pragma unroll
      for (int c = 0; c < 4; ++c) {
        int i = i0 + a, j = j0 + c;
        Bs[i][j] = ((i == j) ? sig : 0.f) - As[i][j];
      }
    if (i0 == j0)
      red[tid >> 4] = Bs[i0][j0] + Bs[i0 + 1][j0 + 1] + Bs[i0 + 2][j0 + 2] + Bs[i0 + 3][j0 + 3];
    __syncthreads();
    for (int s5 = 0; s5 < 18; ++s5) {
      float t = 0.f;
      for (int j = 0; j < 16; ++j) t += red[j];
      float scale = 1.f / (t * t);
      gemm_acc(Bs, Bs, i0, j0, acc);
      __syncthreads();
#pragma unroll
      for (int a = 0; a < 4; ++a)
#pragma unroll
        for (int c = 0; c < 4; ++c) Bs[i0 + a][j0 + c] = acc[a][c] * scale;
      if (i0 == j0)
        red[tid >> 4] = (acc[0][0] + acc[1][1] + acc[2][2] + acc[3][3]) * scale;
      __syncthreads();
    }
    int jstar = 0;
    float best = -1.f;
    for (int j = 0; j < 64; ++j) {
      float d = Bs[j][j];
      if (d > best) {
        best = d;
        jstar = j;
      }
    }
    if (tid < 64) vSh[tid] = Bs[jstar][tid];
    __syncthreads();
    if (tid < 64) {
      float s = 0.f;
      for (int j = 0; j < 64; ++j) s += As[j][tid] * vSh[j];  // A sym
      ySh[tid] = s;
    }
    __syncthreads();
    float vy = 0.f, vv = 0.f;
    for (int j = 0; j < 64; ++j) {
      vy += vSh[j] * ySh[j];
      vv += vSh[j] * vSh[j];
    }
    float lam = vy / vv;
    float lampr = (float)(rho * alpha0 + EPSV) + (float)(1.0 - rho) * lam;
    float w = 1.f / sqrtf(lampr);
    float invn = 1.f / sqrtf(vv);
    if (tid < 64) vS[b * 64 + tid] = vSh[tid] * invn;
    if (tid == 0) {
      float vmu = 0.f;
      for (int j = 0; j < 64; ++j) vmu += vSh[j] * invn * muS[j];
      wvm[b * 2] = w;
      wvm[b * 2 + 1] = vmu;
    }
  }
}

// ---------------- K7: Z = (SxG - w v v^T) x - smu 1^T  via MFMA ----------------
// Same 6-product bf16-split scheme as K1 (error ~6e-8 rel). A = Seff splits
// staged in LDS (30 KB); B = x splits built in registers from coalesced scalar
// loads (lane = column -> 128 B segments). Each wave: 32 cols x all 64 rows
// (acc0 = rows 0-31, acc1 = rows 32-63), so x is read exactly once per block.
// k-map between A and B fragments is identical, which is sufficient for a
// correct contraction; m/n/C-D maps are the K1-verified ones.
__global__ __launch_bounds__(256, 4) void k7_z(const float* __restrict__ x,
                                               const float* __restrict__ SxG,
                                               const float* __restrict__ smuA,
                                               const float* __restrict__ vS,
                                               const float* __restrict__ wvm,
                                               float* __restrict__ z) {
  __shared__ unsigned short S1[64][80], S2[64][80], S3[64][80];
  __shared__ float vsh[64];
  __shared__ float smsh[64];
  const int tid = threadIdx.x;
  const int b = blockIdx.y;
  const int t0 = blockIdx.x * TNB;
  const float w = wvm[b * 2], vmu = wvm[b * 2 + 1];
  if (tid < 64) vsh[tid] = vS[b * 64 + tid];
  __syncthreads();
  {
    const int i = tid >> 2, js = (tid & 3) * 16;
    const float wvi = w * vsh[i];
    const float* sp = SxG + (size_t)b * 4096 + i * 64 + js;
#pragma unroll
    for (int e = 0; e < 16; ++e) {
      float sv = sp[e] - wvi * vsh[js + e];
      unsigned short q1, q2, q3;
      split3(sv, q1, q2, q3);
      S1[i][js + e] = q1;
      S2[i][js + e] = q2;
      S3[i][js + e] = q3;
    }
  }
  if (tid < 64) smsh[tid] = smuA[b * 64 + tid] - w * vsh[tid] * vmu;
  __syncthreads();
  const int wv = tid >> 6, lane = tid & 63;
  const int arow = lane & 31;
  const int krow = (lane >> 5) * 8;
  const int col0 = t0 + wv * 32 + (lane & 31);
  const float* xb = x + (size_t)b * CCH * MMH;
  floatx16 acc0 = {}, acc1 = {};
#pragma unroll
  for (int ks = 0; ks < 4; ++ks) {
    const int kb = ks * 16 + krow;
    float r0[8];
#pragma unroll
    for (int j = 0; j < 8; ++j) r0[j] = xb[(size_t)(kb + j) * MMH + col0];
    bf16x8 B1, B2, B3;
#pragma unroll
    for (int j = 0; j < 8; ++j) {
      unsigned short q1, q2, q3;
      split3(r0[j], q1, q2, q3);
      B1[j] = (short)q1;
      B2[j] = (short)q2;
      B3[j] = (short)q3;
    }
    bf16x8 A1a = *(const bf16x8*)&S1[arow][kb];
    bf16x8 A2a = *(const bf16x8*)&S2[arow][kb];
    bf16x8 A3a = *(const bf16x8*)&S3[arow][kb];
    bf16x8 A1b = *(const bf16x8*)&S1[arow + 32][kb];
    bf16x8 A2b = *(const bf16x8*)&S2[arow + 32][kb];
    bf16x8 A3b = *(const bf16x8*)&S3[arow + 32][kb];
    acc0 = __builtin_amdgcn_mfma_f32_32x32x16_bf16(A1a, B1, acc0, 0, 0, 0);
    acc0 = __builtin_amdgcn_mfma_f32_32x32x16_bf16(A1a, B2, acc0, 0, 0, 0);
    acc0 = __builtin_amdgcn_mfma_f32_32x32x16_bf16(A2a, B1, acc0, 0, 0, 0);
    acc0 = __builtin_amdgcn_mfma_f32_32x32x16_bf16(A2a, B2, acc0, 0, 0, 0);
    acc0 = __builtin_amdgcn_mfma_f32_32x32x16_bf16(A1a, B3, acc0, 0, 0, 0);
    acc0 = __builtin_amdgcn_mfma_f32_32x32x16_bf16(A3a, B1, acc0, 0, 0, 0);
    acc1 = __builtin_amdgcn_mfma_f32_32x32x16_bf16(A1b, B1, acc1, 0, 0, 0);
    acc1 = __builtin_amdgcn_mfma_f32_32x32x16_bf16(A1b, B2, acc1, 0, 0, 0);
    acc1 = __builtin_amdgcn_mfma_f32_32x32x16_bf16(A2b, B1, acc1, 0, 0, 0);
    acc1 = __builtin_amdgcn_mfma_f32_32x32x16_bf16(A2b, B2, acc1, 0, 0, 0);
    acc1 = __builtin_amdgcn_mfma_f32_32x32x16_bf16(A1b, B3, acc1, 0, 0, 0);
    acc1 = __builtin_amdgcn_mfma_f32_32x32x16_bf16(A3b, B1, acc1, 0, 0, 0);
  }
  // C/D: col=lane&31, row=(reg&3)+8*(reg>>2)+4*(lane>>5)  [HW-verified]
#pragma unroll
  for (int r = 0; r < 16; ++r) {
    const int grow = (r & 3) + 8 * (r >> 2) + 4 * (lane >> 5);
    z[((size_t)b * CCH + grow) * MMH + col0] = acc0[r] - smsh[grow];
    z[((size_t)b * CCH + grow + 32) * MMH + col0] = acc1[r] - smsh[grow + 32];
  }
}

extern "C" void kernel_launch(void* const* d_in, const int* in_sizes, int n_in,
                              void* d_out, int out_size, void* d_ws, size_t ws_size,
                              hipStream_t stream) {
  (void)in_sizes;
  (void)n_in;
  (void)out_size;
  (void)ws_size;
  const float* x = (const float*)d_in[0];
  float* z = (float*)d_out;
  // Gram partials live inside d_out (8.5 MB << 128 MB); overwritten by Z in K7.
  float* Gpart = (float*)d_out;                          // 64*8*4096*4 = 8,388,608
  float* rspart = (float*)((char*)d_out + 8388608);      // 64*8*64*4   = 131,072
  char* ws = (char*)d_ws;
  float* cov32 = (float*)(ws + 0);         // 1,048,576
  float* mu32 = (float*)(ws + 1048576);    // 16,384
  double* scal = (double*)(ws + 1064960);  // 2,048
  float* SxG = (float*)(ws + 1067008);     // 1,048,576
  float* smuA = (float*)(ws + 2115584);    // 16,384
  float* vS = (float*)(ws + 2131968);      // 16,384
  float* wvm = (float*)(ws + 2148352);     // 512

  k1_partG<<<dim3(BB * SLICES), dim3(256), 0, stream>>>(x, Gpart, rspart);
  k2_reduce<<<dim3(BB), dim3(256), 0, stream>>>(Gpart, rspart, cov32, mu32, scal);
  k3_eig<<<dim3(2 * BB), dim3(256), 0, stream>>>(cov32, scal, mu32, SxG, smuA, vS, wvm);
  k7_z<<<dim3(MMH / TNB, BB), dim3(256), 0, stream>>>(x, SxG, smuA, vS, wvm, z);
}

// Round 5
// 295.581 us; speedup vs baseline: 1.2427x; 1.0729x over previous
//
#include <hip/hip_runtime.h>
#include <math.h>

#define BB 64
#define CCH 64
#define MMH 8192
#define SLICES 8
#define KSL 1024 /* K per k1 block */
#define KCH 128  /* K per LDS chunk in k1 */
#define TNB 128  /* cols per k7 block */
constexpr double EPSV = 1e-5;

typedef __attribute__((ext_vector_type(8))) short bf16x8;
typedef __attribute__((ext_vector_type(8))) unsigned short u16x8;
typedef __attribute__((ext_vector_type(16))) float floatx16;

// Exact truncation split: f = t1+t2+t3 bit-exact (24-bit mantissa = 3x8 bf16
// significands; bf16 exponent range == fp32 so no underflow).
__device__ __forceinline__ void split3(float f, unsigned short& q1, unsigned short& q2,
                                       unsigned short& q3) {
  unsigned u = __float_as_uint(f);
  q1 = (unsigned short)(u >> 16);
  float r1 = f - __uint_as_float(u & 0xffff0000u);
  unsigned u1 = __float_as_uint(r1);
  q2 = (unsigned short)(u1 >> 16);
  float r2 = r1 - __uint_as_float(u1 & 0xffff0000u);
  q3 = (unsigned short)(__float_as_uint(r2) >> 16);
}

// 6-product split contraction: acc[m][n] += sum_k P[m][k]*Q[n][k]  (error ~2^-32 rel)
// A-frag = row mrow of P-splits, B-frag = row ncol of Q-splits, k-major.
// acc-reg index -> A-operand row, lane&31 -> B-operand row [pinned by K7 pass].
__device__ __forceinline__ floatx16 mm6(const unsigned short (*P1)[72],
                                        const unsigned short (*P2)[72],
                                        const unsigned short (*P3)[72],
                                        const unsigned short (*Q1)[72],
                                        const unsigned short (*Q2)[72],
                                        const unsigned short (*Q3)[72],
                                        int mrow, int ncol, int koff) {
  floatx16 acc = {};
#pragma unroll
  for (int ks = 0; ks < 4; ++ks) {
    const int kk = ks * 16 + koff;
    bf16x8 A1 = *(const bf16x8*)&P1[mrow][kk];
    bf16x8 A2 = *(const bf16x8*)&P2[mrow][kk];
    bf16x8 A3 = *(const bf16x8*)&P3[mrow][kk];
    bf16x8 B1 = *(const bf16x8*)&Q1[ncol][kk];
    bf16x8 B2 = *(const bf16x8*)&Q2[ncol][kk];
    bf16x8 B3 = *(const bf16x8*)&Q3[ncol][kk];
    acc = __builtin_amdgcn_mfma_f32_32x32x16_bf16(A1, B1, acc, 0, 0, 0);
    acc = __builtin_amdgcn_mfma_f32_32x32x16_bf16(A1, B2, acc, 0, 0, 0);
    acc = __builtin_amdgcn_mfma_f32_32x32x16_bf16(A2, B1, acc, 0, 0, 0);
    acc = __builtin_amdgcn_mfma_f32_32x32x16_bf16(A2, B2, acc, 0, 0, 0);
    acc = __builtin_amdgcn_mfma_f32_32x32x16_bf16(A1, B3, acc, 0, 0, 0);
    acc = __builtin_amdgcn_mfma_f32_32x32x16_bf16(A3, B1, acc, 0, 0, 0);
  }
  return acc;
}

// ---------------- K1: bf16-split MFMA partial Gram + row sums ----------------
__global__ __launch_bounds__(256, 3) void k1_partG(const float* __restrict__ x,
                                                   float* __restrict__ Gpart,
                                                   float* __restrict__ rspart) {
  __shared__ unsigned short h1[64][KCH + 8], h2[64][KCH + 8], h3[64][KCH + 8];
  __shared__ float rred[64][4];
  const int tid = threadIdx.x;
  const int b = blockIdx.x / SLICES;
  const int s = blockIdx.x % SLICES;
  const int row = tid >> 2;
  const int seg = (tid & 3) * 32;
  const int wv = tid >> 6;
  const int lane = tid & 63;
  const int rw = wv >> 1, cw = wv & 1;
  const int mrow = 32 * rw + (lane & 31);
  const int ncol = 32 * cw + (lane & 31);
  const int koff = (lane >> 5) * 8;
  const float* xb = x + (size_t)b * CCH * MMH + (size_t)s * KSL;
  floatx16 acc = {};
  float rsum = 0.f;
  for (int c = 0; c < KSL / KCH; ++c) {
    const float* xp = xb + (size_t)row * MMH + c * KCH + seg;
    float v[32];
#pragma unroll
    for (int q = 0; q < 8; ++q) {
      float4 t = *(const float4*)(xp + 4 * q);
      v[4 * q] = t.x;
      v[4 * q + 1] = t.y;
      v[4 * q + 2] = t.z;
      v[4 * q + 3] = t.w;
    }
#pragma unroll
    for (int o = 0; o < 32; ++o) rsum += v[o];
#pragma unroll
    for (int g = 0; g < 4; ++g) {
      u16x8 a1, a2, a3;
#pragma unroll
      for (int j = 0; j < 8; ++j) {
        unsigned short q1, q2, q3;
        split3(v[8 * g + j], q1, q2, q3);
        a1[j] = q1;
        a2[j] = q2;
        a3[j] = q3;
      }
      *(u16x8*)&h1[row][seg + 8 * g] = a1;
      *(u16x8*)&h2[row][seg + 8 * g] = a2;
      *(u16x8*)&h3[row][seg + 8 * g] = a3;
    }
    __syncthreads();
#pragma unroll
    for (int ks = 0; ks < KCH / 16; ++ks) {
      const int kk = ks * 16 + koff;
      bf16x8 A1 = *(const bf16x8*)&h1[mrow][kk];
      bf16x8 A2 = *(const bf16x8*)&h2[mrow][kk];
      bf16x8 A3 = *(const bf16x8*)&h3[mrow][kk];
      bf16x8 B1 = *(const bf16x8*)&h1[ncol][kk];
      bf16x8 B2 = *(const bf16x8*)&h2[ncol][kk];
      bf16x8 B3 = *(const bf16x8*)&h3[ncol][kk];
      acc = __builtin_amdgcn_mfma_f32_32x32x16_bf16(A1, B1, acc, 0, 0, 0);
      acc = __builtin_amdgcn_mfma_f32_32x32x16_bf16(A1, B2, acc, 0, 0, 0);
      acc = __builtin_amdgcn_mfma_f32_32x32x16_bf16(A2, B1, acc, 0, 0, 0);
      acc = __builtin_amdgcn_mfma_f32_32x32x16_bf16(A2, B2, acc, 0, 0, 0);
      acc = __builtin_amdgcn_mfma_f32_32x32x16_bf16(A1, B3, acc, 0, 0, 0);
      acc = __builtin_amdgcn_mfma_f32_32x32x16_bf16(A3, B1, acc, 0, 0, 0);
    }
    __syncthreads();
  }
  // C/D: col=lane&31, row=(reg&3)+8*(reg>>2)+4*(lane>>5)  [HW-verified]
  float* gp = Gpart + ((size_t)(b * SLICES + s)) * 4096;
#pragma unroll
  for (int r = 0; r < 16; ++r) {
    int row32 = (r & 3) + 8 * (r >> 2) + 4 * (lane >> 5);
    gp[(32 * rw + row32) * 64 + 32 * cw + (lane & 31)] = acc[r];
  }
  rred[row][tid & 3] = rsum;
  __syncthreads();
  if (tid < 64) {
    rspart[((size_t)(b * SLICES + s)) * 64 + tid] =
        rred[tid][0] + rred[tid][1] + rred[tid][2] + rred[tid][3];
  }
}

// ---------------- K3 (fused K2): reduce -> cov -> two roles, MFMA gemms ----------------
// Each block recomputes its batch's fp64 reduction (cov in LDS only; no cov32/mu
// round-trip). role 0: Newton-Schulz X=T^{-1/2} (4 iters, 3 MFMA gemms each).
// role 1: 18 repeated squarings of sigma*I - A via MFMA -> dominant eigvec.
// All gemms: C[m][n] = sum_k P[m][k]Q[n][k]; U/Bs^2 are exactly symmetric by
// same-operand construction, so staging at (row,col) = reading row n as B-frag.
__global__ __launch_bounds__(256) void k3_eig(const float* __restrict__ Gpart,
                                              const float* __restrict__ rspart,
                                              float* __restrict__ SxG,
                                              float* __restrict__ smuA,
                                              float* __restrict__ vS,
                                              float* __restrict__ wvm) {
  __shared__ float As[64][64];
  __shared__ float Xs[64][64];
  __shared__ float Bs[64][64];
  __shared__ unsigned short Pa1[64][72], Pa2[64][72], Pa3[64][72];  // A splits (role0)
  __shared__ unsigned short Pp1[64][72], Pp2[64][72], Pp3[64][72];  // X / Bsq splits
  __shared__ unsigned short Pq1[64][72], Pq2[64][72], Pq3[64][72];  // U then V splits
  __shared__ double redd[256];
  __shared__ double muS[64];
  __shared__ double sc[3];
  __shared__ float muF[64];
  __shared__ float red[64];
  __shared__ float redt[2];
  __shared__ float vSh[64];
  __shared__ float ySh[64];
  const int tid = threadIdx.x;
  const int b = blockIdx.x & 63;
  const int role = blockIdx.x >> 6;

  // ---- fused K2: mu + cov (into As) + T1/T2 + rho ----
  if (tid < 64) {
    double r = 0.0;
    for (int s = 0; s < SLICES; ++s) r += (double)rspart[((size_t)(b * SLICES + s)) * 64 + tid];
    double mu = r / (double)MMH;
    muS[tid] = mu;
    muF[tid] = (float)mu;
  }
  __syncthreads();
  {
    const int base = tid * 16;
    const int ii = tid >> 2;
    double g[16];
#pragma unroll
    for (int e = 0; e < 16; ++e) g[e] = 0.0;
    for (int s = 0; s < SLICES; ++s) {
      const float* gp = Gpart + ((size_t)(b * SLICES + s)) * 4096 + base;
#pragma unroll
      for (int q = 0; q < 4; ++q) {
        float4 t = *(const float4*)(gp + 4 * q);
        g[4 * q] += (double)t.x;
        g[4 * q + 1] += (double)t.y;
        g[4 * q + 2] += (double)t.z;
        g[4 * q + 3] += (double)t.w;
      }
    }
    double t1 = 0.0, t2 = 0.0;
#pragma unroll
    for (int e = 0; e < 16; ++e) {
      int j = (base + e) & 63;
      double cv = g[e] / (double)MMH - muS[ii] * muS[j];
      As[ii][(tid & 3) * 16 + e] = (float)cv;
      if (ii == j) t1 += cv;
      t2 += cv * cv;
    }
    redd[tid] = t1;
    __syncthreads();
    for (int st = 128; st > 0; st >>= 1) {
      if (tid < st) redd[tid] += redd[tid + st];
      __syncthreads();
    }
    double T1 = redd[0];
    __syncthreads();
    redd[tid] = t2;
    __syncthreads();
    for (int st = 128; st > 0; st >>= 1) {
      if (tid < st) redd[tid] += redd[tid + st];
      __syncthreads();
    }
    double T2 = redd[0];
    if (tid == 0) {
      double num = ((double)(MMH - 2) / (double)MMH) * T2 + T1 * T1;
      double den = (double)(MMH + 2) * (T2 - T1 * T1 / (double)CCH);
      double r = num / den;
      sc[0] = (r < 1.0) ? r : 1.0;
      sc[1] = T1 / (double)CCH;
      sc[2] = (r >= 1.0) ? 1.0 : 0.0;
    }
  }
  __syncthreads();
  const double rho = sc[0];
  const double alpha0 = sc[1];
  const int clipped = (sc[2] != 0.0);
  const float invsqc = (float)(1.0 / sqrt(alpha0 + EPSV));
  const int wv = tid >> 6, lane = tid & 63;
  const int rw = wv >> 1, cw = wv & 1;
  const int mrow = 32 * rw + (lane & 31);
  const int ncol = 32 * cw + (lane & 31);
  const int koff = (lane >> 5) * 8;

  if (role == 0) {
    if (clipped) {
      for (int k = tid; k < 4096; k += 256) {
        int i = k >> 6, j = k & 63;
        SxG[(size_t)b * 4096 + k] = (i == j) ? invsqc : 0.f;
      }
      if (tid < 64) smuA[b * 64 + tid] = invsqc * muF[tid];
      return;
    }
    const float orhoc = (float)((1.0 - rho) / (alpha0 + EPSV));
    const float dtermc = (float)((rho * alpha0 + EPSV) / (alpha0 + EPSV));
    for (int k = tid; k < 4096; k += 256) {
      int ii = k >> 6, jj = k & 63;
      float a = As[ii][jj];
      unsigned short q1, q2, q3;
      split3(a, q1, q2, q3);
      Pa1[ii][jj] = q1;
      Pa2[ii][jj] = q2;
      Pa3[ii][jj] = q3;
      float t = orhoc * a + ((ii == jj) ? dtermc : 0.f);
      Xs[ii][jj] = ((ii == jj) ? 1.5f : 0.f) - 0.5f * t;
    }
    __syncthreads();
    for (int it = 0; it < 4; ++it) {
      for (int k = tid; k < 4096; k += 256) {
        int ii = k >> 6, jj = k & 63;
        unsigned short q1, q2, q3;
        split3(Xs[ii][jj], q1, q2, q3);
        Pp1[ii][jj] = q1;
        Pp2[ii][jj] = q2;
        Pp3[ii][jj] = q3;
      }
      __syncthreads();
      floatx16 acc = mm6(Pp1, Pp2, Pp3, Pp1, Pp2, Pp3, mrow, ncol, koff);  // U = X*X
      floatx16 ureg = acc;
#pragma unroll
      for (int r = 0; r < 16; ++r) {
        int row32 = (r & 3) + 8 * (r >> 2) + 4 * (lane >> 5);
        int gr = 32 * rw + row32, gc = 32 * cw + (lane & 31);
        unsigned short q1, q2, q3;
        split3(acc[r], q1, q2, q3);
        Pq1[gr][gc] = q1;
        Pq2[gr][gc] = q2;
        Pq3[gr][gc] = q3;
      }
      __syncthreads();
      acc = mm6(Pa1, Pa2, Pa3, Pq1, Pq2, Pq3, mrow, ncol, koff);  // W = A*U
      __syncthreads();  // all waves done reading Pq before overwrite
#pragma unroll
      for (int r = 0; r < 16; ++r) {
        int row32 = (r & 3) + 8 * (r >> 2) + 4 * (lane >> 5);
        int gr = 32 * rw + row32, gc = 32 * cw + (lane & 31);
        float v = orhoc * acc[r] + dtermc * ureg[r];  // V
        unsigned short q1, q2, q3;
        split3(v, q1, q2, q3);
        Pq1[gr][gc] = q1;
        Pq2[gr][gc] = q2;
        Pq3[gr][gc] = q3;
      }
      __syncthreads();
      acc = mm6(Pp1, Pp2, Pp3, Pq1, Pq2, Pq3, mrow, ncol, koff);  // X*V
#pragma unroll
      for (int r = 0; r < 16; ++r) {
        int row32 = (r & 3) + 8 * (r >> 2) + 4 * (lane >> 5);
        int gr = 32 * rw + row32, gc = 32 * cw + (lane & 31);
        Xs[gr][gc] = 1.5f * Xs[gr][gc] - 0.5f * acc[r];
      }
      __syncthreads();
    }
    for (int k = tid; k < 4096; k += 256) SxG[(size_t)b * 4096 + k] = Xs[k >> 6][k & 63] * invsqc;
    if (tid < 64) {
      float sm = 0.f;
      for (int j = 0; j < 64; ++j) sm += Xs[j][tid] * muF[j];  // X sym
      smuA[b * 64 + tid] = sm * invsqc;
    }
  } else {
    if (clipped) {
      if (tid < 64) vS[b * 64 + tid] = (tid == 63) ? 1.f : 0.f;
      if (tid == 0) {
        wvm[b * 2] = invsqc;
        wvm[b * 2 + 1] = muF[63];
      }
      return;
    }
    if (tid < 64) {
      float s = 0.f;
      for (int j = 0; j < 64; ++j) {
        float v = As[j][tid];
        s += (j == tid) ? v : fabsf(v);
      }
      red[tid] = s;
    }
    __syncthreads();
    float sig = 0.f;
    for (int j = 0; j < 64; ++j) sig = fmaxf(sig, red[j]);
    __syncthreads();
    {
      const int i0 = (tid >> 4) << 2, j0 = (tid & 15) << 2;
#pragma unroll
      for (int a = 0; a < 4; ++a)
#pragma unroll
        for (int c = 0; c < 4; ++c) {
          int i = i0 + a, j = j0 + c;
          float bv = ((i == j) ? sig : 0.f) - As[i][j];
          Bs[i][j] = bv;
          unsigned short q1, q2, q3;
          split3(bv, q1, q2, q3);
          Pp1[i][j] = q1;
          Pp2[i][j] = q2;
          Pp3[i][j] = q3;
        }
    }
    __syncthreads();
    if (tid == 0) {
      float t = 0.f;
      for (int j = 0; j < 64; ++j) t += Bs[j][j];
      redt[0] = t;
      redt[1] = 0.f;
    }
    __syncthreads();
    for (int s5 = 0; s5 < 18; ++s5) {
      float t = redt[0] + redt[1];
      float scale = 1.f / (t * t);
      floatx16 acc = mm6(Pp1, Pp2, Pp3, Pp1, Pp2, Pp3, mrow, ncol, koff);
      float dsum = 0.f;
      if (rw == cw) {
#pragma unroll
        for (int r = 0; r < 16; ++r) {
          int row32 = (r & 3) + 8 * (r >> 2) + 4 * (lane >> 5);
          if (row32 == (lane & 31)) dsum += acc[r];
        }
      }
      for (int off = 32; off > 0; off >>= 1) dsum += __shfl_down(dsum, off);
      __syncthreads();  // all waves done reading Pp before overwrite
      if (rw == cw && lane == 0) redt[rw] = dsum * scale;
#pragma unroll
      for (int r = 0; r < 16; ++r) {
        int row32 = (r & 3) + 8 * (r >> 2) + 4 * (lane >> 5);
        int gr = 32 * rw + row32, gc = 32 * cw + (lane & 31);
        float nv = acc[r] * scale;
        Bs[gr][gc] = nv;
        unsigned short q1, q2, q3;
        split3(nv, q1, q2, q3);
        Pp1[gr][gc] = q1;
        Pp2[gr][gc] = q2;
        Pp3[gr][gc] = q3;
      }
      __syncthreads();
    }
    int jstar = 0;
    float best = -1.f;
    for (int j = 0; j < 64; ++j) {
      float d = Bs[j][j];
      if (d > best) {
        best = d;
        jstar = j;
      }
    }
    if (tid < 64) vSh[tid] = Bs[jstar][tid];
    __syncthreads();
    if (tid < 64) {
      float s = 0.f;
      for (int j = 0; j < 64; ++j) s += As[j][tid] * vSh[j];  // A sym
      ySh[tid] = s;
    }
    __syncthreads();
    float vy = 0.f, vv = 0.f;
    for (int j = 0; j < 64; ++j) {
      vy += vSh[j] * ySh[j];
      vv += vSh[j] * vSh[j];
    }
    float lam = vy / vv;
    float lampr = (float)(rho * alpha0 + EPSV) + (float)(1.0 - rho) * lam;
    float w = 1.f / sqrtf(lampr);
    float invn = 1.f / sqrtf(vv);
    if (tid < 64) vS[b * 64 + tid] = vSh[tid] * invn;
    if (tid == 0) {
      float vmu = 0.f;
      for (int j = 0; j < 64; ++j) vmu += vSh[j] * invn * muF[j];
      wvm[b * 2] = w;
      wvm[b * 2 + 1] = vmu;
    }
  }
}

// ---------------- K7: Z = (SxG - w v v^T) x - smu 1^T  via MFMA ----------------
__global__ __launch_bounds__(256, 4) void k7_z(const float* __restrict__ x,
                                               const float* __restrict__ SxG,
                                               const float* __restrict__ smuA,
                                               const float* __restrict__ vS,
                                               const float* __restrict__ wvm,
                                               float* __restrict__ z) {
  __shared__ unsigned short S1[64][80], S2[64][80], S3[64][80];
  __shared__ float vsh[64];
  __shared__ float smsh[64];
  const int tid = threadIdx.x;
  const int b = blockIdx.y;
  const int t0 = blockIdx.x * TNB;
  const float w = wvm[b * 2], vmu = wvm[b * 2 + 1];
  if (tid < 64) vsh[tid] = vS[b * 64 + tid];
  __syncthreads();
  {
    const int i = tid >> 2, js = (tid & 3) * 16;
    const float wvi = w * vsh[i];
    const float* sp = SxG + (size_t)b * 4096 + i * 64 + js;
#pragma unroll
    for (int e = 0; e < 16; ++e) {
      float sv = sp[e] - wvi * vsh[js + e];
      unsigned short q1, q2, q3;
      split3(sv, q1, q2, q3);
      S1[i][js + e] = q1;
      S2[i][js + e] = q2;
      S3[i][js + e] = q3;
    }
  }
  if (tid < 64) smsh[tid] = smuA[b * 64 + tid] - w * vsh[tid] * vmu;
  __syncthreads();
  const int wv = tid >> 6, lane = tid & 63;
  const int arow = lane & 31;
  const int krow = (lane >> 5) * 8;
  const int col0 = t0 + wv * 32 + (lane & 31);
  const float* xb = x + (size_t)b * CCH * MMH;
  floatx16 acc0 = {}, acc1 = {};
#pragma unroll
  for (int ks = 0; ks < 4; ++ks) {
    const int kb = ks * 16 + krow;
    float r0[8];
#pragma unroll
    for (int j = 0; j < 8; ++j) r0[j] = xb[(size_t)(kb + j) * MMH + col0];
    bf16x8 B1, B2, B3;
#pragma unroll
    for (int j = 0; j < 8; ++j) {
      unsigned short q1, q2, q3;
      split3(r0[j], q1, q2, q3);
      B1[j] = (short)q1;
      B2[j] = (short)q2;
      B3[j] = (short)q3;
    }
    bf16x8 A1a = *(const bf16x8*)&S1[arow][kb];
    bf16x8 A2a = *(const bf16x8*)&S2[arow][kb];
    bf16x8 A3a = *(const bf16x8*)&S3[arow][kb];
    bf16x8 A1b = *(const bf16x8*)&S1[arow + 32][kb];
    bf16x8 A2b = *(const bf16x8*)&S2[arow + 32][kb];
    bf16x8 A3b = *(const bf16x8*)&S3[arow + 32][kb];
    acc0 = __builtin_amdgcn_mfma_f32_32x32x16_bf16(A1a, B1, acc0, 0, 0, 0);
    acc0 = __builtin_amdgcn_mfma_f32_32x32x16_bf16(A1a, B2, acc0, 0, 0, 0);
    acc0 = __builtin_amdgcn_mfma_f32_32x32x16_bf16(A2a, B1, acc0, 0, 0, 0);
    acc0 = __builtin_amdgcn_mfma_f32_32x32x16_bf16(A2a, B2, acc0, 0, 0, 0);
    acc0 = __builtin_amdgcn_mfma_f32_32x32x16_bf16(A1a, B3, acc0, 0, 0, 0);
    acc0 = __builtin_amdgcn_mfma_f32_32x32x16_bf16(A3a, B1, acc0, 0, 0, 0);
    acc1 = __builtin_amdgcn_mfma_f32_32x32x16_bf16(A1b, B1, acc1, 0, 0, 0);
    acc1 = __builtin_amdgcn_mfma_f32_32x32x16_bf16(A1b, B2, acc1, 0, 0, 0);
    acc1 = __builtin_amdgcn_mfma_f32_32x32x16_bf16(A2b, B1, acc1, 0, 0, 0);
    acc1 = __builtin_amdgcn_mfma_f32_32x32x16_bf16(A2b, B2, acc1, 0, 0, 0);
    acc1 = __builtin_amdgcn_mfma_f32_32x32x16_bf16(A1b, B3, acc1, 0, 0, 0);
    acc1 = __builtin_amdgcn_mfma_f32_32x32x16_bf16(A3b, B1, acc1, 0, 0, 0);
  }
#pragma unroll
  for (int r = 0; r < 16; ++r) {
    const int grow = (r & 3) + 8 * (r >> 2) + 4 * (lane >> 5);
    z[((size_t)b * CCH + grow) * MMH + col0] = acc0[r] - smsh[grow];
    z[((size_t)b * CCH + grow + 32) * MMH + col0] = acc1[r] - smsh[grow + 32];
  }
}

extern "C" void kernel_launch(void* const* d_in, const int* in_sizes, int n_in,
                              void* d_out, int out_size, void* d_ws, size_t ws_size,
                              hipStream_t stream) {
  (void)in_sizes;
  (void)n_in;
  (void)out_size;
  (void)ws_size;
  const float* x = (const float*)d_in[0];
  float* z = (float*)d_out;
  // Gram partials live inside d_out (8.5 MB << 128 MB); overwritten by Z in K7.
  float* Gpart = (float*)d_out;                      // 64*8*4096*4 = 8,388,608
  float* rspart = (float*)((char*)d_out + 8388608);  // 64*8*64*4   = 131,072
  char* ws = (char*)d_ws;
  float* SxG = (float*)(ws + 0);           // 1,048,576
  float* smuA = (float*)(ws + 1048576);    // 16,384
  float* vS = (float*)(ws + 1064960);      // 16,384
  float* wvm = (float*)(ws + 1081344);     // 512

  k1_partG<<<dim3(BB * SLICES), dim3(256), 0, stream>>>(x, Gpart, rspart);
  k3_eig<<<dim3(2 * BB), dim3(256), 0, stream>>>(Gpart, rspart, SxG, smuA, vS, wvm);
  k7_z<<<dim3(MMH / TNB, BB), dim3(256), 0, stream>>>(x, SxG, smuA, vS, wvm, z);
}

// Round 6
// 283.082 us; speedup vs baseline: 1.2975x; 1.0442x over previous
//
#include <hip/hip_runtime.h>
#include <math.h>

#define BB 64
#define CCH 64
#define MMH 8192
#define SLICES 8
#define KSL 1024 /* K per k1 block */
#define KCH 128  /* K per LDS chunk in k1 */
#define TNB 128  /* cols per k7 block */
constexpr double EPSV = 1e-5;

typedef __attribute__((ext_vector_type(8))) short bf16x8;
typedef __attribute__((ext_vector_type(8))) unsigned short u16x8;
typedef __attribute__((ext_vector_type(16))) float floatx16;

// 2-way truncation split: x = t1 + t2 + r2, |t2| <= 2^-8 |x|, |r2| <= 2^-16 |x|.
// Products kept: t1t1 + t1t2 + t2t1 -> dropped terms ~2^-15 rel per element,
// ~1e-7 per cov entry / ~1e-4 per Z entry after summation: >=100x below the
// 0.03125 algorithmic absmax (stable across 3-split & fp32-VALU variants).
__device__ __forceinline__ void split2(float f, unsigned short& q1, unsigned short& q2) {
  unsigned u = __float_as_uint(f);
  q1 = (unsigned short)(u >> 16);
  float r1 = f - __uint_as_float(u & 0xffff0000u);
  q2 = (unsigned short)(__float_as_uint(r1) >> 16);
}

// 3-product split contraction: acc[m][n] = sum_k P[m][k]*Q[n][k]
// A-frag = row mrow of P-splits, B-frag = row ncol of Q-splits, k-major.
// acc-reg index -> A-operand row, lane&31 -> B-operand row [pinned by K7 pass].
__device__ __forceinline__ floatx16 mm3(const unsigned short (*P1)[72],
                                        const unsigned short (*P2)[72],
                                        const unsigned short (*Q1)[72],
                                        const unsigned short (*Q2)[72],
                                        int mrow, int ncol, int koff) {
  floatx16 acc = {};
#pragma unroll
  for (int ks = 0; ks < 4; ++ks) {
    const int kk = ks * 16 + koff;
    bf16x8 A1 = *(const bf16x8*)&P1[mrow][kk];
    bf16x8 A2 = *(const bf16x8*)&P2[mrow][kk];
    bf16x8 B1 = *(const bf16x8*)&Q1[ncol][kk];
    bf16x8 B2 = *(const bf16x8*)&Q2[ncol][kk];
    acc = __builtin_amdgcn_mfma_f32_32x32x16_bf16(A1, B1, acc, 0, 0, 0);
    acc = __builtin_amdgcn_mfma_f32_32x32x16_bf16(A1, B2, acc, 0, 0, 0);
    acc = __builtin_amdgcn_mfma_f32_32x32x16_bf16(A2, B1, acc, 0, 0, 0);
  }
  return acc;
}

// ---------------- K1: bf16-2split MFMA partial Gram + row sums ----------------
__global__ __launch_bounds__(256, 3) void k1_partG(const float* __restrict__ x,
                                                   float* __restrict__ Gpart,
                                                   float* __restrict__ rspart) {
  __shared__ unsigned short h1[64][KCH + 8], h2[64][KCH + 8];
  __shared__ float rred[64][4];
  const int tid = threadIdx.x;
  const int b = blockIdx.x / SLICES;
  const int s = blockIdx.x % SLICES;
  const int row = tid >> 2;
  const int seg = (tid & 3) * 32;
  const int wv = tid >> 6;
  const int lane = tid & 63;
  const int rw = wv >> 1, cw = wv & 1;
  const int mrow = 32 * rw + (lane & 31);
  const int ncol = 32 * cw + (lane & 31);
  const int koff = (lane >> 5) * 8;
  const float* xb = x + (size_t)b * CCH * MMH + (size_t)s * KSL;
  floatx16 acc = {};
  float rsum = 0.f;
  for (int c = 0; c < KSL / KCH; ++c) {
    const float* xp = xb + (size_t)row * MMH + c * KCH + seg;
    float v[32];
#pragma unroll
    for (int q = 0; q < 8; ++q) {
      float4 t = *(const float4*)(xp + 4 * q);
      v[4 * q] = t.x;
      v[4 * q + 1] = t.y;
      v[4 * q + 2] = t.z;
      v[4 * q + 3] = t.w;
    }
#pragma unroll
    for (int o = 0; o < 32; ++o) rsum += v[o];
#pragma unroll
    for (int g = 0; g < 4; ++g) {
      u16x8 a1, a2;
#pragma unroll
      for (int j = 0; j < 8; ++j) {
        unsigned short q1, q2;
        split2(v[8 * g + j], q1, q2);
        a1[j] = q1;
        a2[j] = q2;
      }
      *(u16x8*)&h1[row][seg + 8 * g] = a1;
      *(u16x8*)&h2[row][seg + 8 * g] = a2;
    }
    __syncthreads();
#pragma unroll
    for (int ks = 0; ks < KCH / 16; ++ks) {
      const int kk = ks * 16 + koff;
      bf16x8 A1 = *(const bf16x8*)&h1[mrow][kk];
      bf16x8 A2 = *(const bf16x8*)&h2[mrow][kk];
      bf16x8 B1 = *(const bf16x8*)&h1[ncol][kk];
      bf16x8 B2 = *(const bf16x8*)&h2[ncol][kk];
      acc = __builtin_amdgcn_mfma_f32_32x32x16_bf16(A1, B1, acc, 0, 0, 0);
      acc = __builtin_amdgcn_mfma_f32_32x32x16_bf16(A1, B2, acc, 0, 0, 0);
      acc = __builtin_amdgcn_mfma_f32_32x32x16_bf16(A2, B1, acc, 0, 0, 0);
    }
    __syncthreads();
  }
  // C/D: col=lane&31, row=(reg&3)+8*(reg>>2)+4*(lane>>5)  [HW-verified]
  float* gp = Gpart + ((size_t)(b * SLICES + s)) * 4096;
#pragma unroll
  for (int r = 0; r < 16; ++r) {
    int row32 = (r & 3) + 8 * (r >> 2) + 4 * (lane >> 5);
    gp[(32 * rw + row32) * 64 + 32 * cw + (lane & 31)] = acc[r];
  }
  rred[row][tid & 3] = rsum;
  __syncthreads();
  if (tid < 64) {
    rspart[((size_t)(b * SLICES + s)) * 64 + tid] =
        rred[tid][0] + rred[tid][1] + rred[tid][2] + rred[tid][3];
  }
}

// ---------------- K3 (fused K2): reduce -> cov -> two roles, MFMA gemms ----------------
// role 0: Newton-Schulz X=T^{-1/2} (4 iters, 3 MFMA gemms each).
// role 1: 18 repeated squarings of sigma*I - A via MFMA -> dominant eigvec.
// All operands are symmetric polynomials of cov -> C = P*Q^T == P*Q.
__global__ __launch_bounds__(256) void k3_eig(const float* __restrict__ Gpart,
                                              const float* __restrict__ rspart,
                                              float* __restrict__ SxG,
                                              float* __restrict__ smuA,
                                              float* __restrict__ vS,
                                              float* __restrict__ wvm) {
  __shared__ float As[64][64];
  __shared__ float Xs[64][64];
  __shared__ float Bs[64][64];
  __shared__ unsigned short Pa1[64][72], Pa2[64][72];  // A splits (role0)
  __shared__ unsigned short Pp1[64][72], Pp2[64][72];  // X / Bsq splits
  __shared__ unsigned short Pq1[64][72], Pq2[64][72];  // U then V splits
  __shared__ double redd[256];
  __shared__ double muS[64];
  __shared__ double sc[3];
  __shared__ float muF[64];
  __shared__ float red[64];
  __shared__ float redt[2];
  __shared__ float vSh[64];
  __shared__ float ySh[64];
  const int tid = threadIdx.x;
  const int b = blockIdx.x & 63;
  const int role = blockIdx.x >> 6;

  // ---- fused K2: mu + cov (into As) + T1/T2 + rho ----
  if (tid < 64) {
    double r = 0.0;
    for (int s = 0; s < SLICES; ++s) r += (double)rspart[((size_t)(b * SLICES + s)) * 64 + tid];
    double mu = r / (double)MMH;
    muS[tid] = mu;
    muF[tid] = (float)mu;
  }
  __syncthreads();
  {
    const int base = tid * 16;
    const int ii = tid >> 2;
    double g[16];
#pragma unroll
    for (int e = 0; e < 16; ++e) g[e] = 0.0;
    for (int s = 0; s < SLICES; ++s) {
      const float* gp = Gpart + ((size_t)(b * SLICES + s)) * 4096 + base;
#pragma unroll
      for (int q = 0; q < 4; ++q) {
        float4 t = *(const float4*)(gp + 4 * q);
        g[4 * q] += (double)t.x;
        g[4 * q + 1] += (double)t.y;
        g[4 * q + 2] += (double)t.z;
        g[4 * q + 3] += (double)t.w;
      }
    }
    double t1 = 0.0, t2 = 0.0;
#pragma unroll
    for (int e = 0; e < 16; ++e) {
      int j = (base + e) & 63;
      double cv = g[e] / (double)MMH - muS[ii] * muS[j];
      As[ii][(tid & 3) * 16 + e] = (float)cv;
      if (ii == j) t1 += cv;
      t2 += cv * cv;
    }
    redd[tid] = t1;
    __syncthreads();
    for (int st = 128; st > 0; st >>= 1) {
      if (tid < st) redd[tid] += redd[tid + st];
      __syncthreads();
    }
    double T1 = redd[0];
    __syncthreads();
    redd[tid] = t2;
    __syncthreads();
    for (int st = 128; st > 0; st >>= 1) {
      if (tid < st) redd[tid] += redd[tid + st];
      __syncthreads();
    }
    double T2 = redd[0];
    if (tid == 0) {
      double num = ((double)(MMH - 2) / (double)MMH) * T2 + T1 * T1;
      double den = (double)(MMH + 2) * (T2 - T1 * T1 / (double)CCH);
      double r = num / den;
      sc[0] = (r < 1.0) ? r : 1.0;
      sc[1] = T1 / (double)CCH;
      sc[2] = (r >= 1.0) ? 1.0 : 0.0;
    }
  }
  __syncthreads();
  const double rho = sc[0];
  const double alpha0 = sc[1];
  const int clipped = (sc[2] != 0.0);
  const float invsqc = (float)(1.0 / sqrt(alpha0 + EPSV));
  const int wv = tid >> 6, lane = tid & 63;
  const int rw = wv >> 1, cw = wv & 1;
  const int mrow = 32 * rw + (lane & 31);
  const int ncol = 32 * cw + (lane & 31);
  const int koff = (lane >> 5) * 8;

  if (role == 0) {
    if (clipped) {
      for (int k = tid; k < 4096; k += 256) {
        int i = k >> 6, j = k & 63;
        SxG[(size_t)b * 4096 + k] = (i == j) ? invsqc : 0.f;
      }
      if (tid < 64) smuA[b * 64 + tid] = invsqc * muF[tid];
      return;
    }
    const float orhoc = (float)((1.0 - rho) / (alpha0 + EPSV));
    const float dtermc = (float)((rho * alpha0 + EPSV) / (alpha0 + EPSV));
    for (int k = tid; k < 4096; k += 256) {
      int ii = k >> 6, jj = k & 63;
      float a = As[ii][jj];
      unsigned short q1, q2;
      split2(a, q1, q2);
      Pa1[ii][jj] = q1;
      Pa2[ii][jj] = q2;
      float t = orhoc * a + ((ii == jj) ? dtermc : 0.f);
      Xs[ii][jj] = ((ii == jj) ? 1.5f : 0.f) - 0.5f * t;
    }
    __syncthreads();
    for (int it = 0; it < 4; ++it) {
      for (int k = tid; k < 4096; k += 256) {
        int ii = k >> 6, jj = k & 63;
        unsigned short q1, q2;
        split2(Xs[ii][jj], q1, q2);
        Pp1[ii][jj] = q1;
        Pp2[ii][jj] = q2;
      }
      __syncthreads();
      floatx16 acc = mm3(Pp1, Pp2, Pp1, Pp2, mrow, ncol, koff);  // U = X*X
      floatx16 ureg = acc;
#pragma unroll
      for (int r = 0; r < 16; ++r) {
        int row32 = (r & 3) + 8 * (r >> 2) + 4 * (lane >> 5);
        int gr = 32 * rw + row32, gc = 32 * cw + (lane & 31);
        unsigned short q1, q2;
        split2(acc[r], q1, q2);
        Pq1[gr][gc] = q1;
        Pq2[gr][gc] = q2;
      }
      __syncthreads();
      acc = mm3(Pa1, Pa2, Pq1, Pq2, mrow, ncol, koff);  // W = A*U
      __syncthreads();  // all waves done reading Pq before overwrite
#pragma unroll
      for (int r = 0; r < 16; ++r) {
        int row32 = (r & 3) + 8 * (r >> 2) + 4 * (lane >> 5);
        int gr = 32 * rw + row32, gc = 32 * cw + (lane & 31);
        float v = orhoc * acc[r] + dtermc * ureg[r];  // V
        unsigned short q1, q2;
        split2(v, q1, q2);
        Pq1[gr][gc] = q1;
        Pq2[gr][gc] = q2;
      }
      __syncthreads();
      acc = mm3(Pp1, Pp2, Pq1, Pq2, mrow, ncol, koff);  // X*V
#pragma unroll
      for (int r = 0; r < 16; ++r) {
        int row32 = (r & 3) + 8 * (r >> 2) + 4 * (lane >> 5);
        int gr = 32 * rw + row32, gc = 32 * cw + (lane & 31);
        Xs[gr][gc] = 1.5f * Xs[gr][gc] - 0.5f * acc[r];
      }
      __syncthreads();
    }
    for (int k = tid; k < 4096; k += 256) SxG[(size_t)b * 4096 + k] = Xs[k >> 6][k & 63] * invsqc;
    if (tid < 64) {
      float sm = 0.f;
      for (int j = 0; j < 64; ++j) sm += Xs[j][tid] * muF[j];  // X sym
      smuA[b * 64 + tid] = sm * invsqc;
    }
  } else {
    if (clipped) {
      if (tid < 64) vS[b * 64 + tid] = (tid == 63) ? 1.f : 0.f;
      if (tid == 0) {
        wvm[b * 2] = invsqc;
        wvm[b * 2 + 1] = muF[63];
      }
      return;
    }
    if (tid < 64) {
      float s = 0.f;
      for (int j = 0; j < 64; ++j) {
        float v = As[j][tid];
        s += (j == tid) ? v : fabsf(v);
      }
      red[tid] = s;
    }
    __syncthreads();
    float sig = 0.f;
    for (int j = 0; j < 64; ++j) sig = fmaxf(sig, red[j]);
    __syncthreads();
    {
      const int i0 = (tid >> 4) << 2, j0 = (tid & 15) << 2;
#pragma unroll
      for (int a = 0; a < 4; ++a)
#pragma unroll
        for (int c = 0; c < 4; ++c) {
          int i = i0 + a, j = j0 + c;
          float bv = ((i == j) ? sig : 0.f) - As[i][j];
          Bs[i][j] = bv;
          unsigned short q1, q2;
          split2(bv, q1, q2);
          Pp1[i][j] = q1;
          Pp2[i][j] = q2;
        }
    }
    __syncthreads();
    if (tid == 0) {
      float t = 0.f;
      for (int j = 0; j < 64; ++j) t += Bs[j][j];
      redt[0] = t;
      redt[1] = 0.f;
    }
    __syncthreads();
    for (int s5 = 0; s5 < 18; ++s5) {
      float t = redt[0] + redt[1];
      float scale = 1.f / (t * t);
      floatx16 acc = mm3(Pp1, Pp2, Pp1, Pp2, mrow, ncol, koff);
      float dsum = 0.f;
      if (rw == cw) {
#pragma unroll
        for (int r = 0; r < 16; ++r) {
          int row32 = (r & 3) + 8 * (r >> 2) + 4 * (lane >> 5);
          if (row32 == (lane & 31)) dsum += acc[r];
        }
      }
      for (int off = 32; off > 0; off >>= 1) dsum += __shfl_down(dsum, off);
      __syncthreads();  // all waves done reading Pp before overwrite
      if (rw == cw && lane == 0) redt[rw] = dsum * scale;
#pragma unroll
      for (int r = 0; r < 16; ++r) {
        int row32 = (r & 3) + 8 * (r >> 2) + 4 * (lane >> 5);
        int gr = 32 * rw + row32, gc = 32 * cw + (lane & 31);
        float nv = acc[r] * scale;
        Bs[gr][gc] = nv;
        unsigned short q1, q2;
        split2(nv, q1, q2);
        Pp1[gr][gc] = q1;
        Pp2[gr][gc] = q2;
      }
      __syncthreads();
    }
    int jstar = 0;
    float best = -1.f;
    for (int j = 0; j < 64; ++j) {
      float d = Bs[j][j];
      if (d > best) {
        best = d;
        jstar = j;
      }
    }
    if (tid < 64) vSh[tid] = Bs[jstar][tid];
    __syncthreads();
    if (tid < 64) {
      float s = 0.f;
      for (int j = 0; j < 64; ++j) s += As[j][tid] * vSh[j];  // A sym
      ySh[tid] = s;
    }
    __syncthreads();
    float vy = 0.f, vv = 0.f;
    for (int j = 0; j < 64; ++j) {
      vy += vSh[j] * ySh[j];
      vv += vSh[j] * vSh[j];
    }
    float lam = vy / vv;
    float lampr = (float)(rho * alpha0 + EPSV) + (float)(1.0 - rho) * lam;
    float w = 1.f / sqrtf(lampr);
    float invn = 1.f / sqrtf(vv);
    if (tid < 64) vS[b * 64 + tid] = vSh[tid] * invn;
    if (tid == 0) {
      float vmu = 0.f;
      for (int j = 0; j < 64; ++j) vmu += vSh[j] * invn * muF[j];
      wvm[b * 2] = w;
      wvm[b * 2 + 1] = vmu;
    }
  }
}

// ---------------- K7: Z = (SxG - w v v^T) x - smu 1^T  via MFMA ----------------
__global__ __launch_bounds__(256, 4) void k7_z(const float* __restrict__ x,
                                               const float* __restrict__ SxG,
                                               const float* __restrict__ smuA,
                                               const float* __restrict__ vS,
                                               const float* __restrict__ wvm,
                                               float* __restrict__ z) {
  __shared__ unsigned short S1[64][80], S2[64][80];
  __shared__ float vsh[64];
  __shared__ float smsh[64];
  const int tid = threadIdx.x;
  const int b = blockIdx.y;
  const int t0 = blockIdx.x * TNB;
  const float w = wvm[b * 2], vmu = wvm[b * 2 + 1];
  if (tid < 64) vsh[tid] = vS[b * 64 + tid];
  __syncthreads();
  {
    const int i = tid >> 2, js = (tid & 3) * 16;
    const float wvi = w * vsh[i];
    const float* sp = SxG + (size_t)b * 4096 + i * 64 + js;
#pragma unroll
    for (int e = 0; e < 16; ++e) {
      float sv = sp[e] - wvi * vsh[js + e];
      unsigned short q1, q2;
      split2(sv, q1, q2);
      S1[i][js + e] = q1;
      S2[i][js + e] = q2;
    }
  }
  if (tid < 64) smsh[tid] = smuA[b * 64 + tid] - w * vsh[tid] * vmu;
  __syncthreads();
  const int wv = tid >> 6, lane = tid & 63;
  const int arow = lane & 31;
  const int krow = (lane >> 5) * 8;
  const int col0 = t0 + wv * 32 + (lane & 31);
  const float* xb = x + (size_t)b * CCH * MMH;
  floatx16 acc0 = {}, acc1 = {};
#pragma unroll
  for (int ks = 0; ks < 4; ++ks) {
    const int kb = ks * 16 + krow;
    float r0[8];
#pragma unroll
    for (int j = 0; j < 8; ++j) r0[j] = xb[(size_t)(kb + j) * MMH + col0];
    bf16x8 B1, B2;
#pragma unroll
    for (int j = 0; j < 8; ++j) {
      unsigned short q1, q2;
      split2(r0[j], q1, q2);
      B1[j] = (short)q1;
      B2[j] = (short)q2;
    }
    bf16x8 A1a = *(const bf16x8*)&S1[arow][kb];
    bf16x8 A2a = *(const bf16x8*)&S2[arow][kb];
    bf16x8 A1b = *(const bf16x8*)&S1[arow + 32][kb];
    bf16x8 A2b = *(const bf16x8*)&S2[arow + 32][kb];
    acc0 = __builtin_amdgcn_mfma_f32_32x32x16_bf16(A1a, B1, acc0, 0, 0, 0);
    acc0 = __builtin_amdgcn_mfma_f32_32x32x16_bf16(A1a, B2, acc0, 0, 0, 0);
    acc0 = __builtin_amdgcn_mfma_f32_32x32x16_bf16(A2a, B1, acc0, 0, 0, 0);
    acc1 = __builtin_amdgcn_mfma_f32_32x32x16_bf16(A1b, B1, acc1, 0, 0, 0);
    acc1 = __builtin_amdgcn_mfma_f32_32x32x16_bf16(A1b, B2, acc1, 0, 0, 0);
    acc1 = __builtin_amdgcn_mfma_f32_32x32x16_bf16(A2b, B1, acc1, 0, 0, 0);
  }
#pragma unroll
  for (int r = 0; r < 16; ++r) {
    const int grow = (r & 3) + 8 * (r >> 2) + 4 * (lane >> 5);
    z[((size_t)b * CCH + grow) * MMH + col0] = acc0[r] - smsh[grow];
    z[((size_t)b * CCH + grow + 32) * MMH + col0] = acc1[r] - smsh[grow + 32];
  }
}

extern "C" void kernel_launch(void* const* d_in, const int* in_sizes, int n_in,
                              void* d_out, int out_size, void* d_ws, size_t ws_size,
                              hipStream_t stream) {
  (void)in_sizes;
  (void)n_in;
  (void)out_size;
  (void)ws_size;
  const float* x = (const float*)d_in[0];
  float* z = (float*)d_out;
  // Gram partials live inside d_out (8.5 MB << 128 MB); overwritten by Z in K7.
  float* Gpart = (float*)d_out;                      // 64*8*4096*4 = 8,388,608
  float* rspart = (float*)((char*)d_out + 8388608);  // 64*8*64*4   = 131,072
  char* ws = (char*)d_ws;
  float* SxG = (float*)(ws + 0);         // 1,048,576
  float* smuA = (float*)(ws + 1048576);  // 16,384
  float* vS = (float*)(ws + 1064960);    // 16,384
  float* wvm = (float*)(ws + 1081344);   // 512

  k1_partG<<<dim3(BB * SLICES), dim3(256), 0, stream>>>(x, Gpart, rspart);
  k3_eig<<<dim3(2 * BB), dim3(256), 0, stream>>>(Gpart, rspart, SxG, smuA, vS, wvm);
  k7_z<<<dim3(MMH / TNB, BB), dim3(256), 0, stream>>>(x, SxG, smuA, vS, wvm, z);
}